// Round 24
// baseline (86.993 us; speedup 1.0000x reference)
//
#include <hip/hip_runtime.h>
#include <hip/hip_bf16.h>
#include <math.h>

// Problem constants
#define NTOK   1024      // 2*512 tokens
#define DIMX   1024
#define INTERX 512
#define NEXP   16
#define RSCALE 2.5f

typedef _Float16 f16x8 __attribute__((ext_vector_type(8)));
typedef _Float16 f16x4v __attribute__((ext_vector_type(4)));
typedef float    f32x4 __attribute__((ext_vector_type(4)));

// fp16 conversion region segment sizes (elements); layout [w13|w2|w13s|w2s|x]
#define N_W13  (NEXP * 2 * INTERX * DIMX)   // 16,777,216
#define N_W2   (NEXP * DIMX * INTERX)       //  8,388,608
#define N_W13S (2 * INTERX * DIMX)          //  1,048,576
#define N_W2S  (DIMX * INTERX)              //    524,288
#define N_X    (NTOK * DIMX)                //  1,048,576

// ws layout (bytes) — proven
#define WS_COUNTS  0                                   // int[16]
#define WS_TOKIDX  256                                 // int[16*1024]
#define WS_SLOTS   (WS_TOKIDX + NEXP * NTOK * 4)       // int[1024*4]
#define WS_WQ      (WS_SLOTS + NTOK * 16)              // float[1024*4]
#define WS_SEL     (WS_WQ + NTOK * 16)                 // int[1024*4]
#define WS_NT      (WS_SEL + NTOK * 16)                // int[1]
#define WS_TE      (WS_NT + 64)                        // int[256]
#define WS_TM      (WS_TE + 1024)                      // int[256]
#define WS_TR      (WS_TM + 1024)                      // int[256]
#define WS_H       (WS_TR + 1024)                      // _Float16[5120*512]
#define WS_YC      (WS_H + (size_t)5120 * 512 * 2)     // _Float16[5120*1024] (4B/elem region)
#define WS_F16     (WS_YC + (size_t)5120 * 1024 * 4)   // _Float16[weights + x]

// XOR-swizzled LDS addressing: row stride 64 halves (128B), k granule 8 halves.
#define SWZ(r, k) ((r) * 64 + ((k) ^ (((r) & 7) << 3)))

// grids: gate 256 blocks; w13|w13s cvt = 17,825,792 elems = 2176 blocks
//        (256 thr x 4 iters x 8); w2|w2s cvt = 8,912,896 elems = 1088 blocks.
#define GATE_BLOCKS  256
#define CVT13_BLOCKS 2176
#define CVT2_BLOCKS  1088
#define FFN_BLOCKS   1088

__device__ __forceinline__ f16x8 ldcvt(const float* __restrict__ p) {
    const float4 a = *(const float4*)p;
    const float4 b = *(const float4*)(p + 4);
    return (f16x8){(_Float16)a.x, (_Float16)a.y, (_Float16)a.z, (_Float16)a.w,
                   (_Float16)b.x, (_Float16)b.y, (_Float16)b.z, (_Float16)b.w};
}

__device__ __forceinline__ f16x8 cvt8(const float4& a, const float4& b) {
    return (f16x8){(_Float16)a.x, (_Float16)a.y, (_Float16)a.z, (_Float16)a.w,
                   (_Float16)b.x, (_Float16)b.y, (_Float16)b.z, (_Float16)b.w};
}

// Direct global->LDS async copy, 16B per lane.
__device__ __forceinline__ void gl_lds16(const _Float16* g, _Float16* l) {
    __builtin_amdgcn_global_load_lds(
        (const __attribute__((address_space(1))) void*)g,
        (__attribute__((address_space(3))) void*)l, 16, 0, 0);
}

// 2-SEGMENT streaming cvt body (round-18's proven-fast codegen; the
// 4-segment variants of rounds 22/23 collapse to 3.6 TB/s, this one ran
// ~7 TB/s as gate_cvt13 in round 18). Load-all -> fence -> store-all.
__device__ __forceinline__ void cvt_body(
    size_t base8, size_t stride8,
    const float* __restrict__ sA, size_t nA, size_t dA,   // segment A
    const float* __restrict__ sB, size_t dB,              // segment B (tail)
    _Float16* __restrict__ dh)
{
    const float* s0; const float* s1; const float* s2; const float* s3;
    size_t d0, d1, d2, d3;
    {
        size_t off = (base8 + 0 * stride8) * 8;
        if (off < nA) { s0 = sA + off; d0 = dA + off; }
        else          { s0 = sB + (off - nA); d0 = dB + (off - nA); }
        off = (base8 + 1 * stride8) * 8;
        if (off < nA) { s1 = sA + off; d1 = dA + off; }
        else          { s1 = sB + (off - nA); d1 = dB + (off - nA); }
        off = (base8 + 2 * stride8) * 8;
        if (off < nA) { s2 = sA + off; d2 = dA + off; }
        else          { s2 = sB + (off - nA); d2 = dB + (off - nA); }
        off = (base8 + 3 * stride8) * 8;
        if (off < nA) { s3 = sA + off; d3 = dA + off; }
        else          { s3 = sB + (off - nA); d3 = dB + (off - nA); }
    }
    const float4 a0 = *(const float4*)s0, b0 = *(const float4*)(s0 + 4);
    const float4 a1 = *(const float4*)s1, b1 = *(const float4*)(s1 + 4);
    const float4 a2 = *(const float4*)s2, b2 = *(const float4*)(s2 + 4);
    const float4 a3 = *(const float4*)s3, b3 = *(const float4*)(s3 + 4);
    __builtin_amdgcn_sched_barrier(0);    // all 8 loads in flight before stores
    *(f16x8*)(dh + d0) = cvt8(a0, b0);
    *(f16x8*)(dh + d1) = cvt8(a1, b1);
    *(f16x8*)(dh + d2) = cvt8(a2, b2);
    *(f16x8*)(dh + d3) = cvt8(a3, b3);
}

// ---------------------------------------------------------------------------
// Fused: blocks [0,256) = gating (+ x->fp16); blocks [256, 256+2176) =
// streaming fp32->fp16 of [w13 | w13s].  (w2|w2s in the standalone cvt2.)
// Exactly round-18's kernel (proven fast).
// ---------------------------------------------------------------------------
__global__ __launch_bounds__(256) void gate_cvt13(
    const float* __restrict__ x, const float* __restrict__ gw,
    const float* __restrict__ gb,
    const float* __restrict__ w13, const float* __restrict__ w13s,
    int* __restrict__ sel, float* __restrict__ wq,
    _Float16* __restrict__ dh, _Float16* __restrict__ xh)
{
    if (blockIdx.x >= GATE_BLOCKS) {
        const size_t base8 = (size_t)(blockIdx.x - GATE_BLOCKS) * 256 + threadIdx.x;
        cvt_body(base8, (size_t)CVT13_BLOCKS * 256,
                 w13, N_W13, 0,                              // w13 -> dh[0..)
                 w13s, (size_t)N_W13 + N_W2,                 // w13s -> dh[N_W13+N_W2..)
                 dh);
        return;
    }

    // ---- gating: one wave per token (4 per block), atomic-free ----
    const int t    = blockIdx.x * 4 + (threadIdx.x >> 6);
    const int lane = threadIdx.x & 63;
    const int e    = lane & 15;
    const int q    = lane >> 4;

    const float4* xq = (const float4*)(x + (size_t)t * DIMX) + q * 64;
    const float4* gq = (const float4*)(gw + (size_t)e * DIMX) + q * 64;
    float s0 = 0.f, s1 = 0.f, s2 = 0.f, s3 = 0.f;
#pragma unroll 8
    for (int i = 0; i < 64; i += 2) {
        const float4 a = xq[i],     b = gq[i];
        const float4 c = xq[i + 1], d = gq[i + 1];
        s0 = fmaf(a.x, b.x, s0); s1 = fmaf(a.y, b.y, s1);
        s2 = fmaf(a.z, b.z, s2); s3 = fmaf(a.w, b.w, s3);
        s0 = fmaf(c.x, d.x, s0); s1 = fmaf(c.y, d.y, s1);
        s2 = fmaf(c.z, d.z, s2); s3 = fmaf(c.w, d.w, s3);
    }
    float acc = (s0 + s1) + (s2 + s3);
    acc += __shfl_xor(acc, 16);
    acc += __shfl_xor(acc, 32);

    {   // fp16 copy of x: lane owns 16 elements of its token's row
        const float* xr = x + (size_t)t * DIMX + lane * 16;
        *(f16x8*)(xh + (size_t)t * DIMX + lane * 16)     = ldcvt(xr);
        *(f16x8*)(xh + (size_t)t * DIMX + lane * 16 + 8) = ldcvt(xr + 8);
    }

    const float sv = 1.f / (1.f + __expf(-acc));
    float v = (lane < 16) ? (sv + gb[e]) : -1e30f;

    float wk0, wk1, wk2, wk3; int ek0, ek1, ek2, ek3;
    float wsum = 0.f;
#pragma unroll
    for (int k = 0; k < 4; ++k) {
        float bestv = v; int besti = lane;
#pragma unroll
        for (int off = 8; off >= 1; off >>= 1) {
            const float ov = __shfl_xor(bestv, off);
            const int   oi = __shfl_xor(besti, off);
            if (ov > bestv || (ov == bestv && oi < besti)) { bestv = ov; besti = oi; }
        }
        besti = __shfl(besti, 0);
        const float sbest = __shfl(sv, besti);
        if (k == 0) { wk0 = sbest; ek0 = besti; }
        if (k == 1) { wk1 = sbest; ek1 = besti; }
        if (k == 2) { wk2 = sbest; ek2 = besti; }
        if (k == 3) { wk3 = sbest; ek3 = besti; }
        wsum += sbest;
        if (lane == besti) v = -1e30f;
    }
    const float scale = RSCALE / wsum;

    if (lane == 0) {
        sel[t * 4 + 0] = ek0;  wq[t * 4 + 0] = wk0 * scale;
        sel[t * 4 + 1] = ek1;  wq[t * 4 + 1] = wk1 * scale;
        sel[t * 4 + 2] = ek2;  wq[t * 4 + 2] = wk2 * scale;
        sel[t * 4 + 3] = ek3;  wq[t * 4 + 3] = wk3 * scale;
    }
}

// ---------------------------------------------------------------------------
// Standalone w2|w2s fp32->fp16 cvt — same proven 2-segment body.
// (Never tried standalone before: rounds 16-19 hid it inside ffn1g, which
// cost ~25 µs of GEMM time every time. Serial cost here: ~8-10 µs.)
// ---------------------------------------------------------------------------
__global__ __launch_bounds__(256) void cvt2(
    const float* __restrict__ w2, const float* __restrict__ w2s,
    _Float16* __restrict__ dh)
{
    const size_t base8 = (size_t)blockIdx.x * 256 + threadIdx.x;
    cvt_body(base8, (size_t)CVT2_BLOCKS * 256,
             w2, N_W2, (size_t)N_W13,                        // w2  -> dh[N_W13..)
             w2s, (size_t)N_W13 + N_W2 + N_W13S,             // w2s -> dh[..]
             dh);
}

// ---------------------------------------------------------------------------
// Build per-expert token lists + COMPACT M-TILE QUEUE (e, m0, row0).
// ONE block, LDS atomics only.
// ---------------------------------------------------------------------------
__global__ __launch_bounds__(1024) void build(
    const int* __restrict__ sel,
    int* __restrict__ counts, int* __restrict__ tok_idx,
    int* __restrict__ slots,
    int* __restrict__ n_tiles, int* __restrict__ tile_e,
    int* __restrict__ tile_m0, int* __restrict__ tile_r0)
{
    __shared__ int lc[NEXP];
    const int t = threadIdx.x;
    if (t < NEXP) lc[t] = 0;
    __syncthreads();

    int e0 = sel[t * 4 + 0], e1 = sel[t * 4 + 1];
    int e2 = sel[t * 4 + 2], e3 = sel[t * 4 + 3];
    int p0 = atomicAdd(&lc[e0], 1);
    int p1 = atomicAdd(&lc[e1], 1);
    int p2 = atomicAdd(&lc[e2], 1);
    int p3 = atomicAdd(&lc[e3], 1);
    tok_idx[e0 * NTOK + p0] = t;  slots[t * 4 + 0] = (e0 << 10) | p0;
    tok_idx[e1 * NTOK + p1] = t;  slots[t * 4 + 1] = (e1 << 10) | p1;
    tok_idx[e2 * NTOK + p2] = t;  slots[t * 4 + 2] = (e2 << 10) | p2;
    tok_idx[e3 * NTOK + p3] = t;  slots[t * 4 + 3] = (e3 << 10) | p3;

    __syncthreads();
    if (t < NEXP) counts[t] = lc[t];
    if (t == 0) {
        int nt = 0, row = 0;
        for (int e = 0; e <= NEXP; ++e) {
            const int c = (e == NEXP) ? NTOK : lc[e];
            for (int m0 = 0; m0 < c; m0 += 128) {
                tile_e[nt]  = e;
                tile_m0[nt] = m0;
                tile_r0[nt] = row + m0;
                ++nt;
            }
            row += c;
        }
        n_tiles[0] = nt;
    }
}

// Counted-vmcnt pipeline helpers (rule #18: sched_barrier after waitcnt/barrier)
#define WAITV8()  do { asm volatile("s_waitcnt vmcnt(8)" ::: "memory"); \
                       __builtin_amdgcn_sched_barrier(0); } while (0)
#define WAITV0()  do { asm volatile("s_waitcnt vmcnt(0)" ::: "memory"); \
                       __builtin_amdgcn_sched_barrier(0); } while (0)
#define RBAR()    do { __builtin_amdgcn_s_barrier(); \
                       __builtin_amdgcn_sched_barrier(0); } while (0)

// ---------------------------------------------------------------------------
// FFN1 (gload_lds, 128x128 tile, compact tile queue, counted-vmcnt pipeline).
// PURE GEMM (proven ~22-25 µs when not polluted with cvt work).
// ---------------------------------------------------------------------------
__global__ __launch_bounds__(256, 2) void ffn1g(
    const _Float16* __restrict__ xh,
    const _Float16* __restrict__ w13h, const _Float16* __restrict__ w13sh,
    const int* __restrict__ counts, const int* __restrict__ tok_idx,
    const int* __restrict__ n_tiles, const int* __restrict__ tile_e,
    const int* __restrict__ tile_m0, const int* __restrict__ tile_r0,
    _Float16* __restrict__ h)
{
    const int tile = blockIdx.x >> 3;
    if (tile >= n_tiles[0]) return;
    const int y  = blockIdx.x & 7;
    const int e  = tile_e[tile];
    const int m0 = tile_m0[tile];
    const int rowbase = tile_r0[tile] - m0;   // so rowbase + m is the global row
    const int Me = (e == NEXP) ? NTOK : counts[e];
    const int g0 = y * 64;

    const int tid = threadIdx.x, lane = tid & 63;
    const int wid = tid >> 6;
    const int wm = wid >> 1, wn = wid & 1;
    const int li = lane & 15, rk = (lane >> 4) * 8;

    const _Float16* Wh = (e == NEXP) ? w13sh : (w13h + (size_t)e * (2 * INTERX) * DIMX);

    __shared__ _Float16 T[2][256 * 64];   // 64 KB

    const int lrow = lane >> 3;           // row within 8-row chunk
    const int lc   = (lane & 7) ^ lrow;   // pre-swizzled logical k-chunk
    const _Float16* src[8];
    int ldsoff[8];
#pragma unroll
    for (int j = 0; j < 8; ++j) {
        const int c = wid * 8 + j;        // chunk 0..31
        const int r = c * 8 + lrow;
        ldsoff[j] = c * 512;
        if (r < 128) {                    // A: gathered token row
            int ma = m0 + r; if (ma >= Me) ma = Me - 1;
            const int tok = (e == NEXP) ? ma : tok_idx[e * NTOK + ma];
            src[j] = xh + (size_t)tok * DIMX + lc * 8;
        } else {                          // B: w13 row in frag order
            const int rb = r - 128;
            const int bwn = rb >> 6, bf = (rb >> 4) & 3, bli = rb & 15;
            const int wrow = ((bf & 2) ? INTERX : 0) + g0 + bwn * 32 + (bf & 1) * 16 + bli;
            src[j] = Wh + (size_t)wrow * DIMX + lc * 8;
        }
    }

    f32x4 acc[4][4];
#pragma unroll
    for (int i = 0; i < 4; ++i)
#pragma unroll
        for (int f = 0; f < 4; ++f) acc[i][f] = (f32x4){0.f, 0.f, 0.f, 0.f};

    auto STAGE = [&](int b, int k0) {
#pragma unroll
        for (int j = 0; j < 8; ++j)
            gl_lds16(src[j] + k0, &T[b][ldsoff[j]]);
    };
    auto MM = [&](int b) {
#pragma unroll
        for (int kk = 0; kk < 64; kk += 32) {
            f16x8 afr[4], bfr[4];
#pragma unroll
            for (int i = 0; i < 4; ++i) {
                const int r = wm * 64 + i * 16 + li;
                afr[i] = *(const f16x8*)&T[b][SWZ(r, kk + rk)];
            }
#pragma unroll
            for (int f = 0; f < 4; ++f) {
                const int r = 128 + wn * 64 + f * 16 + li;
                bfr[f] = *(const f16x8*)&T[b][SWZ(r, kk + rk)];
            }
#pragma unroll
            for (int i = 0; i < 4; ++i)
#pragma unroll
                for (int f = 0; f < 4; ++f)
                    acc[i][f] = __builtin_amdgcn_mfma_f32_16x16x32_f16(
                        afr[i], bfr[f], acc[i][f], 0, 0, 0);
        }
    };

    STAGE(0, 0);
    WAITV0();
    RBAR();
    int cur = 0;
#pragma unroll
    for (int t = 0; t < DIMX / 64; ++t) {
        if (t + 1 < DIMX / 64) {
            STAGE(cur ^ 1, (t + 1) * 64);   // 8 loads stay in flight over MFMA
            WAITV8();                        // only waits the PREVIOUS stage
        } else {
            WAITV0();
        }
        RBAR();                              // all waves' prev-stage loads landed
        MM(cur);
        RBAR();                              // buf cur free for overwrite
        cur ^= 1;
    }

    // epilogue: frag f (gate) pairs with f+2 (up), same lane -> same h-col
#pragma unroll
    for (int i = 0; i < 4; ++i) {
#pragma unroll
        for (int q = 0; q < 4; ++q) {
            const int m = m0 + wm * 64 + i * 16 + (lane >> 4) * 4 + q;
            if (m >= Me) continue;
            _Float16* hp = h + (size_t)(rowbase + m) * INTERX + g0 + wn * 32 + li;
#pragma unroll
            for (int f = 0; f < 2; ++f) {
                const float g = acc[i][f][q];
                const float u = acc[i][f + 2][q];
                hp[f * 16] = (_Float16)(g * u / (1.f + __expf(-g)));
            }
        }
    }
}

// ---------------------------------------------------------------------------
// FFN2 (gload_lds, 128x128 tile, compact tile queue, counted-vmcnt pipeline):
// yc[row, n0..n0+127] = h_row @ w2_e^T (fp16 out).
// ---------------------------------------------------------------------------
__global__ __launch_bounds__(256, 2) void ffn2g(
    const _Float16* __restrict__ w2h, const _Float16* __restrict__ w2sh,
    const int* __restrict__ counts, const _Float16* __restrict__ h,
    const int* __restrict__ n_tiles, const int* __restrict__ tile_e,
    const int* __restrict__ tile_m0, const int* __restrict__ tile_r0,
    _Float16* __restrict__ yc)
{
    const int tile = blockIdx.x >> 3;
    if (tile >= n_tiles[0]) return;
    const int y  = blockIdx.x & 7;
    const int e  = tile_e[tile];
    const int m0 = tile_m0[tile];
    const int rowbase = tile_r0[tile] - m0;
    const int Me = (e == NEXP) ? NTOK : counts[e];
    const int n0 = y * 128;

    const int tid = threadIdx.x, lane = tid & 63;
    const int wid = tid >> 6;
    const int wm = wid >> 1, wn = wid & 1;
    const int li = lane & 15, rk = (lane >> 4) * 8;

    const _Float16* Wh = (e == NEXP) ? w2sh : (w2h + (size_t)e * DIMX * INTERX);

    __shared__ _Float16 T[2][256 * 64];   // 64 KB

    const int lrow = lane >> 3;
    const int lc   = (lane & 7) ^ lrow;
    const _Float16* src[8];
    int ldsoff[8];
#pragma unroll
    for (int j = 0; j < 8; ++j) {
        const int c = wid * 8 + j;
        const int r = c * 8 + lrow;
        ldsoff[j] = c * 512;
        if (r < 128) {                    // A: h row (rowbase+m0+r < 5120 always)
            src[j] = h + (size_t)(rowbase + m0 + r) * INTERX + lc * 8;
        } else {                          // B: w2 row n0 + rb (linear)
            const int rb = r - 128;
            src[j] = Wh + (size_t)(n0 + rb) * INTERX + lc * 8;
        }
    }

    f32x4 acc[4][4];
#pragma unroll
    for (int i = 0; i < 4; ++i)
#pragma unroll
        for (int f = 0; f < 4; ++f) acc[i][f] = (f32x4){0.f, 0.f, 0.f, 0.f};

    auto STAGE = [&](int b, int k0) {
#pragma unroll
        for (int j = 0; j < 8; ++j)
            gl_lds16(src[j] + k0, &T[b][ldsoff[j]]);
    };
    auto MM = [&](int b) {
#pragma unroll
        for (int kk = 0; kk < 64; kk += 32) {
            f16x8 afr[4], bfr[4];
#pragma unroll
            for (int i = 0; i < 4; ++i) {
                const int r = wm * 64 + i * 16 + li;
                afr[i] = *(const f16x8*)&T[b][SWZ(r, kk + rk)];
            }
#pragma unroll
            for (int f = 0; f < 4; ++f) {
                const int r = 128 + wn * 64 + f * 16 + li;
                bfr[f] = *(const f16x8*)&T[b][SWZ(r, kk + rk)];
            }
#pragma unroll
            for (int i = 0; i < 4; ++i)
#pragma unroll
                for (int f = 0; f < 4; ++f)
                    acc[i][f] = __builtin_amdgcn_mfma_f32_16x16x32_f16(
                        afr[i], bfr[f], acc[i][f], 0, 0, 0);
        }
    };

    STAGE(0, 0);
    WAITV0();
    RBAR();
    int cur = 0;
#pragma unroll
    for (int t = 0; t < INTERX / 64; ++t) {
        if (t + 1 < INTERX / 64) {
            STAGE(cur ^ 1, (t + 1) * 64);
            WAITV8();
        } else {
            WAITV0();
        }
        RBAR();
        MM(cur);
        RBAR();
        cur ^= 1;
    }

#pragma unroll
    for (int i = 0; i < 4; ++i) {
#pragma unroll
        for (int q = 0; q < 4; ++q) {
            const int m = m0 + wm * 64 + i * 16 + (lane >> 4) * 4 + q;
            if (m >= Me) continue;
            _Float16* yp = yc + (size_t)(rowbase + m) * DIMX + n0 + wn * 64 + li;
#pragma unroll
            for (int f = 0; f < 4; ++f)
                yp[f * 16] = (_Float16)acc[i][f][q];
        }
    }
}

// ---------------------------------------------------------------------------
// Combine: out[t,:] = yc[shared_row(t),:] + sum_k wq[t,k] * yc[row(t,k),:]
// ---------------------------------------------------------------------------
__global__ __launch_bounds__(256) void combine(
    const int* __restrict__ counts,
    const int* __restrict__ slots,
    const float* __restrict__ wq,
    const _Float16* __restrict__ yc,
    float* __restrict__ out)
{
    __shared__ int soff[NEXP];
    if (threadIdx.x < NEXP) {
        int o = 0;
        for (int i = 0; i < (int)threadIdx.x; ++i) o += counts[i];
        soff[threadIdx.x] = o;
    }
    __syncthreads();

    const int t = blockIdx.x;
    const int tid = threadIdx.x;                 // 256 threads x 4 cols = 1024
    const f16x4v* ycv = (const f16x4v*)yc;
    const f16x4v b = ycv[(size_t)(4096 + t) * 256 + tid];
    float a0 = (float)b[0], a1 = (float)b[1], a2 = (float)b[2], a3 = (float)b[3];
#pragma unroll
    for (int k = 0; k < 4; ++k) {
        const int s   = slots[t * 4 + k];
        const int e   = s >> 10, pos = s & 1023;
        const float w = wq[t * 4 + k];
        const f16x4v v = ycv[(size_t)(soff[e] + pos) * 256 + tid];
        a0 = fmaf(w, (float)v[0], a0); a1 = fmaf(w, (float)v[1], a1);
        a2 = fmaf(w, (float)v[2], a2); a3 = fmaf(w, (float)v[3], a3);
    }
    ((float4*)out)[(size_t)t * 256 + tid] = make_float4(a0, a1, a2, a3);
}

// ---------------------------------------------------------------------------
extern "C" void kernel_launch(void* const* d_in, const int* in_sizes, int n_in,
                              void* d_out, int out_size, void* d_ws, size_t ws_size,
                              hipStream_t stream)
{
    const float* x    = (const float*)d_in[0];
    // d_in[1] = input_ids (unused)
    const float* gw   = (const float*)d_in[2];
    const float* gb   = (const float*)d_in[3];
    const float* w13  = (const float*)d_in[4];
    const float* w2   = (const float*)d_in[5];
    const float* w13s = (const float*)d_in[6];
    const float* w2s  = (const float*)d_in[7];
    float* out = (float*)d_out;

    char* ws = (char*)d_ws;
    int*       counts  = (int*)(ws + WS_COUNTS);
    int*       tok_idx = (int*)(ws + WS_TOKIDX);
    int*       slots   = (int*)(ws + WS_SLOTS);
    float*     wq      = (float*)(ws + WS_WQ);
    int*       sel     = (int*)(ws + WS_SEL);
    int*       n_tiles = (int*)(ws + WS_NT);
    int*       tile_e  = (int*)(ws + WS_TE);
    int*       tile_m0 = (int*)(ws + WS_TM);
    int*       tile_r0 = (int*)(ws + WS_TR);
    _Float16*  h       = (_Float16*)(ws + WS_H);
    _Float16*  yc      = (_Float16*)(ws + WS_YC);
    _Float16*  dh      = (_Float16*)(ws + WS_F16);
    _Float16*  w13h    = dh;
    _Float16*  w2h     = w13h + N_W13;
    _Float16*  w13sh   = w2h + N_W2;
    _Float16*  w2sh    = w13sh + N_W13S;
    _Float16*  xh      = w2sh + N_W2S;

    // Fused gate + w13|w13s conversion (2-segment fast body)
    gate_cvt13<<<GATE_BLOCKS + CVT13_BLOCKS, 256, 0, stream>>>(
        x, gw, gb, w13, w13s, sel, wq, dh, xh);
    // Standalone w2|w2s conversion (same fast body)
    cvt2<<<CVT2_BLOCKS, 256, 0, stream>>>(w2, w2s, dh);
    build<<<1, 1024, 0, stream>>>(sel, counts, tok_idx, slots,
                                  n_tiles, tile_e, tile_m0, tile_r0);

    // Pure GEMMs (compact tile queue, contiguous active ids)
    ffn1g<<<FFN_BLOCKS, 256, 0, stream>>>(xh, w13h, w13sh, counts, tok_idx,
                                          n_tiles, tile_e, tile_m0, tile_r0, h);
    ffn2g<<<FFN_BLOCKS, 256, 0, stream>>>(w2h, w2sh, counts, h,
                                          n_tiles, tile_e, tile_m0, tile_r0, yc);
    combine<<<NTOK, 256, 0, stream>>>(counts, slots, wq, yc, out);
}

// Round 25
// 83.653 us; speedup vs baseline: 1.0399x; 1.0399x over previous
//
#include <hip/hip_runtime.h>
#include <hip/hip_bf16.h>
#include <math.h>

// Problem constants
#define NTOK   1024      // 2*512 tokens
#define DIMX   1024
#define INTERX 512
#define NEXP   16
#define RSCALE 2.5f

typedef _Float16 f16x8 __attribute__((ext_vector_type(8)));
typedef _Float16 f16x4v __attribute__((ext_vector_type(4)));
typedef float    f32x4 __attribute__((ext_vector_type(4)));

// fp16 conversion region segment sizes (elements); layout [w13|w2|w13s|w2s|x]
#define N_W13  (NEXP * 2 * INTERX * DIMX)   // 16,777,216
#define N_W2   (NEXP * DIMX * INTERX)       //  8,388,608
#define N_W13S (2 * INTERX * DIMX)          //  1,048,576
#define N_W2S  (DIMX * INTERX)              //    524,288
#define N_X    (NTOK * DIMX)                //  1,048,576

// ws layout (bytes) — proven
#define WS_COUNTS  0                                   // int[16]
#define WS_TOKIDX  256                                 // int[16*1024]
#define WS_SLOTS   (WS_TOKIDX + NEXP * NTOK * 4)       // int[1024*4]
#define WS_WQ      (WS_SLOTS + NTOK * 16)              // float[1024*4]
#define WS_SEL     (WS_WQ + NTOK * 16)                 // int[1024*4]
#define WS_NT      (WS_SEL + NTOK * 16)                // int[1]
#define WS_TE      (WS_NT + 64)                        // int[256]
#define WS_TM      (WS_TE + 1024)                      // int[256]
#define WS_TR      (WS_TM + 1024)                      // int[256]
#define WS_H       (WS_TR + 1024)                      // _Float16[5120*512]
#define WS_YC      (WS_H + (size_t)5120 * 512 * 2)     // _Float16[5120*1024] (4B/elem region)
#define WS_F16     (WS_YC + (size_t)5120 * 1024 * 4)   // _Float16[weights + x]

// XOR-swizzled LDS addressing: row stride 64 halves (128B), k granule 8 halves.
#define SWZ(r, k) ((r) * 64 + ((k) ^ (((r) & 7) << 3)))

// grids: gate 256; w13|w13s cvt = 2176 blocks (256thr x 4it x 8el);
//        w2|w2s cvt = 1088 blocks. One fused dispatch of 3520 blocks.
#define GATE_BLOCKS  256
#define CVT13_BLOCKS 2176
#define CVT2_BLOCKS  1088
#define FFN_BLOCKS   1088

__device__ __forceinline__ f16x8 ldcvt(const float* __restrict__ p) {
    const float4 a = *(const float4*)p;
    const float4 b = *(const float4*)(p + 4);
    return (f16x8){(_Float16)a.x, (_Float16)a.y, (_Float16)a.z, (_Float16)a.w,
                   (_Float16)b.x, (_Float16)b.y, (_Float16)b.z, (_Float16)b.w};
}

__device__ __forceinline__ f16x8 cvt8(const float4& a, const float4& b) {
    return (f16x8){(_Float16)a.x, (_Float16)a.y, (_Float16)a.z, (_Float16)a.w,
                   (_Float16)b.x, (_Float16)b.y, (_Float16)b.z, (_Float16)b.w};
}

// Direct global->LDS async copy, 16B per lane.
__device__ __forceinline__ void gl_lds16(const _Float16* g, _Float16* l) {
    __builtin_amdgcn_global_load_lds(
        (const __attribute__((address_space(1))) void*)g,
        (__attribute__((address_space(3))) void*)l, 16, 0, 0);
}

// 2-SEGMENT streaming cvt body (proven-fast codegen; 4-segment variants
// collapse to 3.6 TB/s). Load-all -> fence -> store-all.
__device__ __forceinline__ void cvt_body(
    size_t base8, size_t stride8,
    const float* __restrict__ sA, size_t nA, size_t dA,   // segment A
    const float* __restrict__ sB, size_t dB,              // segment B (tail)
    _Float16* __restrict__ dh)
{
    const float* s0; const float* s1; const float* s2; const float* s3;
    size_t d0, d1, d2, d3;
    {
        size_t off = (base8 + 0 * stride8) * 8;
        if (off < nA) { s0 = sA + off; d0 = dA + off; }
        else          { s0 = sB + (off - nA); d0 = dB + (off - nA); }
        off = (base8 + 1 * stride8) * 8;
        if (off < nA) { s1 = sA + off; d1 = dA + off; }
        else          { s1 = sB + (off - nA); d1 = dB + (off - nA); }
        off = (base8 + 2 * stride8) * 8;
        if (off < nA) { s2 = sA + off; d2 = dA + off; }
        else          { s2 = sB + (off - nA); d2 = dB + (off - nA); }
        off = (base8 + 3 * stride8) * 8;
        if (off < nA) { s3 = sA + off; d3 = dA + off; }
        else          { s3 = sB + (off - nA); d3 = dB + (off - nA); }
    }
    const float4 a0 = *(const float4*)s0, b0 = *(const float4*)(s0 + 4);
    const float4 a1 = *(const float4*)s1, b1 = *(const float4*)(s1 + 4);
    const float4 a2 = *(const float4*)s2, b2 = *(const float4*)(s2 + 4);
    const float4 a3 = *(const float4*)s3, b3 = *(const float4*)(s3 + 4);
    __builtin_amdgcn_sched_barrier(0);    // all 8 loads in flight before stores
    *(f16x8*)(dh + d0) = cvt8(a0, b0);
    *(f16x8*)(dh + d1) = cvt8(a1, b1);
    *(f16x8*)(dh + d2) = cvt8(a2, b2);
    *(f16x8*)(dh + d3) = cvt8(a3, b3);
}

// ---------------------------------------------------------------------------
// Fused (3 populations): blocks [0,256) = gating (+ x->fp16);
// [256, 2432) = w13|w13s cvt (2-seg body); [2432, 3520) = w2|w2s cvt
// (its OWN 2-seg body — not round-22's slow 4-segment merge).
// ---------------------------------------------------------------------------
__global__ __launch_bounds__(256) void gate_cvt(
    const float* __restrict__ x, const float* __restrict__ gw,
    const float* __restrict__ gb,
    const float* __restrict__ w13, const float* __restrict__ w2,
    const float* __restrict__ w13s, const float* __restrict__ w2s,
    int* __restrict__ sel, float* __restrict__ wq,
    _Float16* __restrict__ dh, _Float16* __restrict__ xh)
{
    if (blockIdx.x >= GATE_BLOCKS + CVT13_BLOCKS) {
        // ---- w2|w2s cvt population ----
        const size_t base8 = (size_t)(blockIdx.x - GATE_BLOCKS - CVT13_BLOCKS) * 256
                           + threadIdx.x;
        cvt_body(base8, (size_t)CVT2_BLOCKS * 256,
                 w2, N_W2, (size_t)N_W13,                    // w2  -> dh[N_W13..)
                 w2s, (size_t)N_W13 + N_W2 + N_W13S,         // w2s -> dh[..]
                 dh);
        return;
    }
    if (blockIdx.x >= GATE_BLOCKS) {
        // ---- w13|w13s cvt population ----
        const size_t base8 = (size_t)(blockIdx.x - GATE_BLOCKS) * 256 + threadIdx.x;
        cvt_body(base8, (size_t)CVT13_BLOCKS * 256,
                 w13, N_W13, 0,                              // w13 -> dh[0..)
                 w13s, (size_t)N_W13 + N_W2,                 // w13s -> dh[N_W13+N_W2..)
                 dh);
        return;
    }

    // ---- gating: one wave per token (4 per block), atomic-free ----
    const int t    = blockIdx.x * 4 + (threadIdx.x >> 6);
    const int lane = threadIdx.x & 63;
    const int e    = lane & 15;
    const int q    = lane >> 4;

    const float4* xq = (const float4*)(x + (size_t)t * DIMX) + q * 64;
    const float4* gq = (const float4*)(gw + (size_t)e * DIMX) + q * 64;
    float s0 = 0.f, s1 = 0.f, s2 = 0.f, s3 = 0.f;
#pragma unroll 8
    for (int i = 0; i < 64; i += 2) {
        const float4 a = xq[i],     b = gq[i];
        const float4 c = xq[i + 1], d = gq[i + 1];
        s0 = fmaf(a.x, b.x, s0); s1 = fmaf(a.y, b.y, s1);
        s2 = fmaf(a.z, b.z, s2); s3 = fmaf(a.w, b.w, s3);
        s0 = fmaf(c.x, d.x, s0); s1 = fmaf(c.y, d.y, s1);
        s2 = fmaf(c.z, d.z, s2); s3 = fmaf(c.w, d.w, s3);
    }
    float acc = (s0 + s1) + (s2 + s3);
    acc += __shfl_xor(acc, 16);
    acc += __shfl_xor(acc, 32);

    {   // fp16 copy of x: lane owns 16 elements of its token's row
        const float* xr = x + (size_t)t * DIMX + lane * 16;
        *(f16x8*)(xh + (size_t)t * DIMX + lane * 16)     = ldcvt(xr);
        *(f16x8*)(xh + (size_t)t * DIMX + lane * 16 + 8) = ldcvt(xr + 8);
    }

    const float sv = 1.f / (1.f + __expf(-acc));
    float v = (lane < 16) ? (sv + gb[e]) : -1e30f;

    float wk0, wk1, wk2, wk3; int ek0, ek1, ek2, ek3;
    float wsum = 0.f;
#pragma unroll
    for (int k = 0; k < 4; ++k) {
        float bestv = v; int besti = lane;
#pragma unroll
        for (int off = 8; off >= 1; off >>= 1) {
            const float ov = __shfl_xor(bestv, off);
            const int   oi = __shfl_xor(besti, off);
            if (ov > bestv || (ov == bestv && oi < besti)) { bestv = ov; besti = oi; }
        }
        besti = __shfl(besti, 0);
        const float sbest = __shfl(sv, besti);
        if (k == 0) { wk0 = sbest; ek0 = besti; }
        if (k == 1) { wk1 = sbest; ek1 = besti; }
        if (k == 2) { wk2 = sbest; ek2 = besti; }
        if (k == 3) { wk3 = sbest; ek3 = besti; }
        wsum += sbest;
        if (lane == besti) v = -1e30f;
    }
    const float scale = RSCALE / wsum;

    if (lane == 0) {
        sel[t * 4 + 0] = ek0;  wq[t * 4 + 0] = wk0 * scale;
        sel[t * 4 + 1] = ek1;  wq[t * 4 + 1] = wk1 * scale;
        sel[t * 4 + 2] = ek2;  wq[t * 4 + 2] = wk2 * scale;
        sel[t * 4 + 3] = ek3;  wq[t * 4 + 3] = wk3 * scale;
    }
}

// ---------------------------------------------------------------------------
// Build per-expert token lists + COMPACT M-TILE QUEUE (e, m0, row0).
// ONE block, LDS atomics only.
// ---------------------------------------------------------------------------
__global__ __launch_bounds__(1024) void build(
    const int* __restrict__ sel,
    int* __restrict__ counts, int* __restrict__ tok_idx,
    int* __restrict__ slots,
    int* __restrict__ n_tiles, int* __restrict__ tile_e,
    int* __restrict__ tile_m0, int* __restrict__ tile_r0)
{
    __shared__ int lc[NEXP];
    const int t = threadIdx.x;
    if (t < NEXP) lc[t] = 0;
    __syncthreads();

    int e0 = sel[t * 4 + 0], e1 = sel[t * 4 + 1];
    int e2 = sel[t * 4 + 2], e3 = sel[t * 4 + 3];
    int p0 = atomicAdd(&lc[e0], 1);
    int p1 = atomicAdd(&lc[e1], 1);
    int p2 = atomicAdd(&lc[e2], 1);
    int p3 = atomicAdd(&lc[e3], 1);
    tok_idx[e0 * NTOK + p0] = t;  slots[t * 4 + 0] = (e0 << 10) | p0;
    tok_idx[e1 * NTOK + p1] = t;  slots[t * 4 + 1] = (e1 << 10) | p1;
    tok_idx[e2 * NTOK + p2] = t;  slots[t * 4 + 2] = (e2 << 10) | p2;
    tok_idx[e3 * NTOK + p3] = t;  slots[t * 4 + 3] = (e3 << 10) | p3;

    __syncthreads();
    if (t < NEXP) counts[t] = lc[t];
    if (t == 0) {
        int nt = 0, row = 0;
        for (int e = 0; e <= NEXP; ++e) {
            const int c = (e == NEXP) ? NTOK : lc[e];
            for (int m0 = 0; m0 < c; m0 += 128) {
                tile_e[nt]  = e;
                tile_m0[nt] = m0;
                tile_r0[nt] = row + m0;
                ++nt;
            }
            row += c;
        }
        n_tiles[0] = nt;
    }
}

// Counted-vmcnt pipeline helpers (rule #18: sched_barrier after waitcnt/barrier)
#define WAITV8()  do { asm volatile("s_waitcnt vmcnt(8)" ::: "memory"); \
                       __builtin_amdgcn_sched_barrier(0); } while (0)
#define WAITV0()  do { asm volatile("s_waitcnt vmcnt(0)" ::: "memory"); \
                       __builtin_amdgcn_sched_barrier(0); } while (0)
#define RBAR()    do { __builtin_amdgcn_s_barrier(); \
                       __builtin_amdgcn_sched_barrier(0); } while (0)

// ---------------------------------------------------------------------------
// FFN1 (gload_lds, 128x128 tile, compact tile queue, counted-vmcnt pipeline).
// PURE GEMM.
// ---------------------------------------------------------------------------
__global__ __launch_bounds__(256, 2) void ffn1g(
    const _Float16* __restrict__ xh,
    const _Float16* __restrict__ w13h, const _Float16* __restrict__ w13sh,
    const int* __restrict__ counts, const int* __restrict__ tok_idx,
    const int* __restrict__ n_tiles, const int* __restrict__ tile_e,
    const int* __restrict__ tile_m0, const int* __restrict__ tile_r0,
    _Float16* __restrict__ h)
{
    const int tile = blockIdx.x >> 3;
    if (tile >= n_tiles[0]) return;
    const int y  = blockIdx.x & 7;
    const int e  = tile_e[tile];
    const int m0 = tile_m0[tile];
    const int rowbase = tile_r0[tile] - m0;   // so rowbase + m is the global row
    const int Me = (e == NEXP) ? NTOK : counts[e];
    const int g0 = y * 64;

    const int tid = threadIdx.x, lane = tid & 63;
    const int wid = tid >> 6;
    const int wm = wid >> 1, wn = wid & 1;
    const int li = lane & 15, rk = (lane >> 4) * 8;

    const _Float16* Wh = (e == NEXP) ? w13sh : (w13h + (size_t)e * (2 * INTERX) * DIMX);

    __shared__ _Float16 T[2][256 * 64];   // 64 KB

    const int lrow = lane >> 3;           // row within 8-row chunk
    const int lc   = (lane & 7) ^ lrow;   // pre-swizzled logical k-chunk
    const _Float16* src[8];
    int ldsoff[8];
#pragma unroll
    for (int j = 0; j < 8; ++j) {
        const int c = wid * 8 + j;        // chunk 0..31
        const int r = c * 8 + lrow;
        ldsoff[j] = c * 512;
        if (r < 128) {                    // A: gathered token row
            int ma = m0 + r; if (ma >= Me) ma = Me - 1;
            const int tok = (e == NEXP) ? ma : tok_idx[e * NTOK + ma];
            src[j] = xh + (size_t)tok * DIMX + lc * 8;
        } else {                          // B: w13 row in frag order
            const int rb = r - 128;
            const int bwn = rb >> 6, bf = (rb >> 4) & 3, bli = rb & 15;
            const int wrow = ((bf & 2) ? INTERX : 0) + g0 + bwn * 32 + (bf & 1) * 16 + bli;
            src[j] = Wh + (size_t)wrow * DIMX + lc * 8;
        }
    }

    f32x4 acc[4][4];
#pragma unroll
    for (int i = 0; i < 4; ++i)
#pragma unroll
        for (int f = 0; f < 4; ++f) acc[i][f] = (f32x4){0.f, 0.f, 0.f, 0.f};

    auto STAGE = [&](int b, int k0) {
#pragma unroll
        for (int j = 0; j < 8; ++j)
            gl_lds16(src[j] + k0, &T[b][ldsoff[j]]);
    };
    auto MM = [&](int b) {
#pragma unroll
        for (int kk = 0; kk < 64; kk += 32) {
            f16x8 afr[4], bfr[4];
#pragma unroll
            for (int i = 0; i < 4; ++i) {
                const int r = wm * 64 + i * 16 + li;
                afr[i] = *(const f16x8*)&T[b][SWZ(r, kk + rk)];
            }
#pragma unroll
            for (int f = 0; f < 4; ++f) {
                const int r = 128 + wn * 64 + f * 16 + li;
                bfr[f] = *(const f16x8*)&T[b][SWZ(r, kk + rk)];
            }
#pragma unroll
            for (int i = 0; i < 4; ++i)
#pragma unroll
                for (int f = 0; f < 4; ++f)
                    acc[i][f] = __builtin_amdgcn_mfma_f32_16x16x32_f16(
                        afr[i], bfr[f], acc[i][f], 0, 0, 0);
        }
    };

    STAGE(0, 0);
    WAITV0();
    RBAR();
    int cur = 0;
#pragma unroll
    for (int t = 0; t < DIMX / 64; ++t) {
        if (t + 1 < DIMX / 64) {
            STAGE(cur ^ 1, (t + 1) * 64);   // 8 loads stay in flight over MFMA
            WAITV8();                        // only waits the PREVIOUS stage
        } else {
            WAITV0();
        }
        RBAR();                              // all waves' prev-stage loads landed
        MM(cur);
        RBAR();                              // buf cur free for overwrite
        cur ^= 1;
    }

    // epilogue: frag f (gate) pairs with f+2 (up), same lane -> same h-col
#pragma unroll
    for (int i = 0; i < 4; ++i) {
#pragma unroll
        for (int q = 0; q < 4; ++q) {
            const int m = m0 + wm * 64 + i * 16 + (lane >> 4) * 4 + q;
            if (m >= Me) continue;
            _Float16* hp = h + (size_t)(rowbase + m) * INTERX + g0 + wn * 32 + li;
#pragma unroll
            for (int f = 0; f < 2; ++f) {
                const float g = acc[i][f][q];
                const float u = acc[i][f + 2][q];
                hp[f * 16] = (_Float16)(g * u / (1.f + __expf(-g)));
            }
        }
    }
}

// ---------------------------------------------------------------------------
// FFN2 (gload_lds, 128x128 tile, compact tile queue, counted-vmcnt pipeline):
// yc[row, n0..n0+127] = h_row @ w2_e^T (fp16 out).
// ---------------------------------------------------------------------------
__global__ __launch_bounds__(256, 2) void ffn2g(
    const _Float16* __restrict__ w2h, const _Float16* __restrict__ w2sh,
    const int* __restrict__ counts, const _Float16* __restrict__ h,
    const int* __restrict__ n_tiles, const int* __restrict__ tile_e,
    const int* __restrict__ tile_m0, const int* __restrict__ tile_r0,
    _Float16* __restrict__ yc)
{
    const int tile = blockIdx.x >> 3;
    if (tile >= n_tiles[0]) return;
    const int y  = blockIdx.x & 7;
    const int e  = tile_e[tile];
    const int m0 = tile_m0[tile];
    const int rowbase = tile_r0[tile] - m0;
    const int Me = (e == NEXP) ? NTOK : counts[e];
    const int n0 = y * 128;

    const int tid = threadIdx.x, lane = tid & 63;
    const int wid = tid >> 6;
    const int wm = wid >> 1, wn = wid & 1;
    const int li = lane & 15, rk = (lane >> 4) * 8;

    const _Float16* Wh = (e == NEXP) ? w2sh : (w2h + (size_t)e * DIMX * INTERX);

    __shared__ _Float16 T[2][256 * 64];   // 64 KB

    const int lrow = lane >> 3;
    const int lc   = (lane & 7) ^ lrow;
    const _Float16* src[8];
    int ldsoff[8];
#pragma unroll
    for (int j = 0; j < 8; ++j) {
        const int c = wid * 8 + j;
        const int r = c * 8 + lrow;
        ldsoff[j] = c * 512;
        if (r < 128) {                    // A: h row (rowbase+m0+r < 5120 always)
            src[j] = h + (size_t)(rowbase + m0 + r) * INTERX + lc * 8;
        } else {                          // B: w2 row n0 + rb (linear)
            const int rb = r - 128;
            src[j] = Wh + (size_t)(n0 + rb) * INTERX + lc * 8;
        }
    }

    f32x4 acc[4][4];
#pragma unroll
    for (int i = 0; i < 4; ++i)
#pragma unroll
        for (int f = 0; f < 4; ++f) acc[i][f] = (f32x4){0.f, 0.f, 0.f, 0.f};

    auto STAGE = [&](int b, int k0) {
#pragma unroll
        for (int j = 0; j < 8; ++j)
            gl_lds16(src[j] + k0, &T[b][ldsoff[j]]);
    };
    auto MM = [&](int b) {
#pragma unroll
        for (int kk = 0; kk < 64; kk += 32) {
            f16x8 afr[4], bfr[4];
#pragma unroll
            for (int i = 0; i < 4; ++i) {
                const int r = wm * 64 + i * 16 + li;
                afr[i] = *(const f16x8*)&T[b][SWZ(r, kk + rk)];
            }
#pragma unroll
            for (int f = 0; f < 4; ++f) {
                const int r = 128 + wn * 64 + f * 16 + li;
                bfr[f] = *(const f16x8*)&T[b][SWZ(r, kk + rk)];
            }
#pragma unroll
            for (int i = 0; i < 4; ++i)
#pragma unroll
                for (int f = 0; f < 4; ++f)
                    acc[i][f] = __builtin_amdgcn_mfma_f32_16x16x32_f16(
                        afr[i], bfr[f], acc[i][f], 0, 0, 0);
        }
    };

    STAGE(0, 0);
    WAITV0();
    RBAR();
    int cur = 0;
#pragma unroll
    for (int t = 0; t < INTERX / 64; ++t) {
        if (t + 1 < INTERX / 64) {
            STAGE(cur ^ 1, (t + 1) * 64);
            WAITV8();
        } else {
            WAITV0();
        }
        RBAR();
        MM(cur);
        RBAR();
        cur ^= 1;
    }

#pragma unroll
    for (int i = 0; i < 4; ++i) {
#pragma unroll
        for (int q = 0; q < 4; ++q) {
            const int m = m0 + wm * 64 + i * 16 + (lane >> 4) * 4 + q;
            if (m >= Me) continue;
            _Float16* yp = yc + (size_t)(rowbase + m) * DIMX + n0 + wn * 64 + li;
#pragma unroll
            for (int f = 0; f < 4; ++f)
                yp[f * 16] = (_Float16)acc[i][f][q];
        }
    }
}

// ---------------------------------------------------------------------------
// Combine: out[t,:] = yc[shared_row(t),:] + sum_k wq[t,k] * yc[row(t,k),:]
// ---------------------------------------------------------------------------
__global__ __launch_bounds__(256) void combine(
    const int* __restrict__ counts,
    const int* __restrict__ slots,
    const float* __restrict__ wq,
    const _Float16* __restrict__ yc,
    float* __restrict__ out)
{
    __shared__ int soff[NEXP];
    if (threadIdx.x < NEXP) {
        int o = 0;
        for (int i = 0; i < (int)threadIdx.x; ++i) o += counts[i];
        soff[threadIdx.x] = o;
    }
    __syncthreads();

    const int t = blockIdx.x;
    const int tid = threadIdx.x;                 // 256 threads x 4 cols = 1024
    const f16x4v* ycv = (const f16x4v*)yc;
    const f16x4v b = ycv[(size_t)(4096 + t) * 256 + tid];
    float a0 = (float)b[0], a1 = (float)b[1], a2 = (float)b[2], a3 = (float)b[3];
#pragma unroll
    for (int k = 0; k < 4; ++k) {
        const int s   = slots[t * 4 + k];
        const int e   = s >> 10, pos = s & 1023;
        const float w = wq[t * 4 + k];
        const f16x4v v = ycv[(size_t)(soff[e] + pos) * 256 + tid];
        a0 = fmaf(w, (float)v[0], a0); a1 = fmaf(w, (float)v[1], a1);
        a2 = fmaf(w, (float)v[2], a2); a3 = fmaf(w, (float)v[3], a3);
    }
    ((float4*)out)[(size_t)t * 256 + tid] = make_float4(a0, a1, a2, a3);
}

// ---------------------------------------------------------------------------
extern "C" void kernel_launch(void* const* d_in, const int* in_sizes, int n_in,
                              void* d_out, int out_size, void* d_ws, size_t ws_size,
                              hipStream_t stream)
{
    const float* x    = (const float*)d_in[0];
    // d_in[1] = input_ids (unused)
    const float* gw   = (const float*)d_in[2];
    const float* gb   = (const float*)d_in[3];
    const float* w13  = (const float*)d_in[4];
    const float* w2   = (const float*)d_in[5];
    const float* w13s = (const float*)d_in[6];
    const float* w2s  = (const float*)d_in[7];
    float* out = (float*)d_out;

    char* ws = (char*)d_ws;
    int*       counts  = (int*)(ws + WS_COUNTS);
    int*       tok_idx = (int*)(ws + WS_TOKIDX);
    int*       slots   = (int*)(ws + WS_SLOTS);
    float*     wq      = (float*)(ws + WS_WQ);
    int*       sel     = (int*)(ws + WS_SEL);
    int*       n_tiles = (int*)(ws + WS_NT);
    int*       tile_e  = (int*)(ws + WS_TE);
    int*       tile_m0 = (int*)(ws + WS_TM);
    int*       tile_r0 = (int*)(ws + WS_TR);
    _Float16*  h       = (_Float16*)(ws + WS_H);
    _Float16*  yc      = (_Float16*)(ws + WS_YC);
    _Float16*  dh      = (_Float16*)(ws + WS_F16);
    _Float16*  w13h    = dh;
    _Float16*  w2h     = w13h + N_W13;
    _Float16*  w13sh   = w2h + N_W2;
    _Float16*  w2sh    = w13sh + N_W13S;
    _Float16*  xh      = w2sh + N_W2S;

    // Fused gate + FULL weight conversion (3 populations, two 2-seg bodies)
    gate_cvt<<<GATE_BLOCKS + CVT13_BLOCKS + CVT2_BLOCKS, 256, 0, stream>>>(
        x, gw, gb, w13, w2, w13s, w2s, sel, wq, dh, xh);
    build<<<1, 1024, 0, stream>>>(sel, counts, tok_idx, slots,
                                  n_tiles, tile_e, tile_m0, tile_r0);

    // Pure GEMMs (compact tile queue, contiguous active ids)
    ffn1g<<<FFN_BLOCKS, 256, 0, stream>>>(xh, w13h, w13sh, counts, tok_idx,
                                          n_tiles, tile_e, tile_m0, tile_r0, h);
    ffn2g<<<FFN_BLOCKS, 256, 0, stream>>>(w2h, w2sh, counts, h,
                                          n_tiles, tile_e, tile_m0, tile_r0, yc);
    combine<<<NTOK, 256, 0, stream>>>(counts, slots, wq, yc, out);
}

// Round 26
// 83.168 us; speedup vs baseline: 1.0460x; 1.0058x over previous
//
#include <hip/hip_runtime.h>
#include <hip/hip_bf16.h>
#include <math.h>

// Problem constants
#define NTOK   1024      // 2*512 tokens
#define DIMX   1024
#define INTERX 512
#define NEXP   16
#define RSCALE 2.5f

typedef _Float16 f16x8 __attribute__((ext_vector_type(8)));
typedef _Float16 f16x4v __attribute__((ext_vector_type(4)));
typedef float    f32x4 __attribute__((ext_vector_type(4)));

// fp16 conversion region segment sizes (elements); layout [w13|w2|w13s|w2s|x]
#define N_W13  (NEXP * 2 * INTERX * DIMX)   // 16,777,216
#define N_W2   (NEXP * DIMX * INTERX)       //  8,388,608
#define N_W13S (2 * INTERX * DIMX)          //  1,048,576
#define N_W2S  (DIMX * INTERX)              //    524,288
#define N_X    (NTOK * DIMX)                //  1,048,576

// ws layout (bytes) — proven
#define WS_COUNTS  0                                   // int[16]
#define WS_TOKIDX  256                                 // int[16*1024]
#define WS_SLOTS   (WS_TOKIDX + NEXP * NTOK * 4)       // int[1024*4]
#define WS_WQ      (WS_SLOTS + NTOK * 16)              // float[1024*4]
#define WS_SEL     (WS_WQ + NTOK * 16)                 // int[1024*4]
#define WS_NT      (WS_SEL + NTOK * 16)                // int[1]
#define WS_TE      (WS_NT + 64)                        // int[256]
#define WS_TM      (WS_TE + 1024)                      // int[256]
#define WS_TR      (WS_TM + 1024)                      // int[256]
#define WS_H       (WS_TR + 1024)                      // _Float16[5120*512]
#define WS_YC      (WS_H + (size_t)5120 * 512 * 2)     // _Float16[5120*1024] (4B/elem region)
#define WS_F16     (WS_YC + (size_t)5120 * 1024 * 4)   // _Float16[weights + x]

// XOR-swizzled LDS addressing: row stride 64 halves (128B), k granule 8 halves.
#define SWZ(r, k) ((r) * 64 + ((k) ^ (((r) & 7) << 3)))

// grids: gate 256; w13|w13s cvt = 2176 blocks (256thr x 4it x 8el);
//        w2|w2s cvt = 1088 blocks. One fused dispatch of 3520 blocks.
#define GATE_BLOCKS  256
#define CVT13_BLOCKS 2176
#define CVT2_BLOCKS  1088
#define FFN_BLOCKS   1088

__device__ __forceinline__ f16x8 ldcvt(const float* __restrict__ p) {
    const float4 a = *(const float4*)p;
    const float4 b = *(const float4*)(p + 4);
    return (f16x8){(_Float16)a.x, (_Float16)a.y, (_Float16)a.z, (_Float16)a.w,
                   (_Float16)b.x, (_Float16)b.y, (_Float16)b.z, (_Float16)b.w};
}

__device__ __forceinline__ f16x8 cvt8(const float4& a, const float4& b) {
    return (f16x8){(_Float16)a.x, (_Float16)a.y, (_Float16)a.z, (_Float16)a.w,
                   (_Float16)b.x, (_Float16)b.y, (_Float16)b.z, (_Float16)b.w};
}

// Direct global->LDS async copy, 16B per lane.
__device__ __forceinline__ void gl_lds16(const _Float16* g, _Float16* l) {
    __builtin_amdgcn_global_load_lds(
        (const __attribute__((address_space(1))) void*)g,
        (__attribute__((address_space(3))) void*)l, 16, 0, 0);
}

// 2-SEGMENT streaming cvt body (proven-fast codegen; 4-segment variants
// collapse to 3.6 TB/s). Load-all -> fence -> store-all.
__device__ __forceinline__ void cvt_body(
    size_t base8, size_t stride8,
    const float* __restrict__ sA, size_t nA, size_t dA,   // segment A
    const float* __restrict__ sB, size_t dB,              // segment B (tail)
    _Float16* __restrict__ dh)
{
    const float* s0; const float* s1; const float* s2; const float* s3;
    size_t d0, d1, d2, d3;
    {
        size_t off = (base8 + 0 * stride8) * 8;
        if (off < nA) { s0 = sA + off; d0 = dA + off; }
        else          { s0 = sB + (off - nA); d0 = dB + (off - nA); }
        off = (base8 + 1 * stride8) * 8;
        if (off < nA) { s1 = sA + off; d1 = dA + off; }
        else          { s1 = sB + (off - nA); d1 = dB + (off - nA); }
        off = (base8 + 2 * stride8) * 8;
        if (off < nA) { s2 = sA + off; d2 = dA + off; }
        else          { s2 = sB + (off - nA); d2 = dB + (off - nA); }
        off = (base8 + 3 * stride8) * 8;
        if (off < nA) { s3 = sA + off; d3 = dA + off; }
        else          { s3 = sB + (off - nA); d3 = dB + (off - nA); }
    }
    const float4 a0 = *(const float4*)s0, b0 = *(const float4*)(s0 + 4);
    const float4 a1 = *(const float4*)s1, b1 = *(const float4*)(s1 + 4);
    const float4 a2 = *(const float4*)s2, b2 = *(const float4*)(s2 + 4);
    const float4 a3 = *(const float4*)s3, b3 = *(const float4*)(s3 + 4);
    __builtin_amdgcn_sched_barrier(0);    // all 8 loads in flight before stores
    *(f16x8*)(dh + d0) = cvt8(a0, b0);
    *(f16x8*)(dh + d1) = cvt8(a1, b1);
    *(f16x8*)(dh + d2) = cvt8(a2, b2);
    *(f16x8*)(dh + d3) = cvt8(a3, b3);
}

// ---------------------------------------------------------------------------
// Fused (3 populations): blocks [0,256) = gating (+ x->fp16);
// [256, 2432) = w13|w13s cvt (2-seg body); [2432, 3520) = w2|w2s cvt
// (its OWN 2-seg body — not round-22's slow 4-segment merge).
// ---------------------------------------------------------------------------
__global__ __launch_bounds__(256) void gate_cvt(
    const float* __restrict__ x, const float* __restrict__ gw,
    const float* __restrict__ gb,
    const float* __restrict__ w13, const float* __restrict__ w2,
    const float* __restrict__ w13s, const float* __restrict__ w2s,
    int* __restrict__ sel, float* __restrict__ wq,
    _Float16* __restrict__ dh, _Float16* __restrict__ xh)
{
    if (blockIdx.x >= GATE_BLOCKS + CVT13_BLOCKS) {
        // ---- w2|w2s cvt population ----
        const size_t base8 = (size_t)(blockIdx.x - GATE_BLOCKS - CVT13_BLOCKS) * 256
                           + threadIdx.x;
        cvt_body(base8, (size_t)CVT2_BLOCKS * 256,
                 w2, N_W2, (size_t)N_W13,                    // w2  -> dh[N_W13..)
                 w2s, (size_t)N_W13 + N_W2 + N_W13S,         // w2s -> dh[..]
                 dh);
        return;
    }
    if (blockIdx.x >= GATE_BLOCKS) {
        // ---- w13|w13s cvt population ----
        const size_t base8 = (size_t)(blockIdx.x - GATE_BLOCKS) * 256 + threadIdx.x;
        cvt_body(base8, (size_t)CVT13_BLOCKS * 256,
                 w13, N_W13, 0,                              // w13 -> dh[0..)
                 w13s, (size_t)N_W13 + N_W2,                 // w13s -> dh[N_W13+N_W2..)
                 dh);
        return;
    }

    // ---- gating: one wave per token (4 per block), atomic-free ----
    const int t    = blockIdx.x * 4 + (threadIdx.x >> 6);
    const int lane = threadIdx.x & 63;
    const int e    = lane & 15;
    const int q    = lane >> 4;

    const float4* xq = (const float4*)(x + (size_t)t * DIMX) + q * 64;
    const float4* gq = (const float4*)(gw + (size_t)e * DIMX) + q * 64;
    float s0 = 0.f, s1 = 0.f, s2 = 0.f, s3 = 0.f;
#pragma unroll 8
    for (int i = 0; i < 64; i += 2) {
        const float4 a = xq[i],     b = gq[i];
        const float4 c = xq[i + 1], d = gq[i + 1];
        s0 = fmaf(a.x, b.x, s0); s1 = fmaf(a.y, b.y, s1);
        s2 = fmaf(a.z, b.z, s2); s3 = fmaf(a.w, b.w, s3);
        s0 = fmaf(c.x, d.x, s0); s1 = fmaf(c.y, d.y, s1);
        s2 = fmaf(c.z, d.z, s2); s3 = fmaf(c.w, d.w, s3);
    }
    float acc = (s0 + s1) + (s2 + s3);
    acc += __shfl_xor(acc, 16);
    acc += __shfl_xor(acc, 32);

    {   // fp16 copy of x: lane owns 16 elements of its token's row
        const float* xr = x + (size_t)t * DIMX + lane * 16;
        *(f16x8*)(xh + (size_t)t * DIMX + lane * 16)     = ldcvt(xr);
        *(f16x8*)(xh + (size_t)t * DIMX + lane * 16 + 8) = ldcvt(xr + 8);
    }

    const float sv = 1.f / (1.f + __expf(-acc));
    float v = (lane < 16) ? (sv + gb[e]) : -1e30f;

    float wk0, wk1, wk2, wk3; int ek0, ek1, ek2, ek3;
    float wsum = 0.f;
#pragma unroll
    for (int k = 0; k < 4; ++k) {
        float bestv = v; int besti = lane;
#pragma unroll
        for (int off = 8; off >= 1; off >>= 1) {
            const float ov = __shfl_xor(bestv, off);
            const int   oi = __shfl_xor(besti, off);
            if (ov > bestv || (ov == bestv && oi < besti)) { bestv = ov; besti = oi; }
        }
        besti = __shfl(besti, 0);
        const float sbest = __shfl(sv, besti);
        if (k == 0) { wk0 = sbest; ek0 = besti; }
        if (k == 1) { wk1 = sbest; ek1 = besti; }
        if (k == 2) { wk2 = sbest; ek2 = besti; }
        if (k == 3) { wk3 = sbest; ek3 = besti; }
        wsum += sbest;
        if (lane == besti) v = -1e30f;
    }
    const float scale = RSCALE / wsum;

    if (lane == 0) {
        sel[t * 4 + 0] = ek0;  wq[t * 4 + 0] = wk0 * scale;
        sel[t * 4 + 1] = ek1;  wq[t * 4 + 1] = wk1 * scale;
        sel[t * 4 + 2] = ek2;  wq[t * 4 + 2] = wk2 * scale;
        sel[t * 4 + 3] = ek3;  wq[t * 4 + 3] = wk3 * scale;
    }
}

// ---------------------------------------------------------------------------
// Build per-expert token lists + COMPACT M-TILE QUEUE (e, m0, row0).
// ONE block, LDS atomics only.
// ---------------------------------------------------------------------------
__global__ __launch_bounds__(1024) void build(
    const int* __restrict__ sel,
    int* __restrict__ counts, int* __restrict__ tok_idx,
    int* __restrict__ slots,
    int* __restrict__ n_tiles, int* __restrict__ tile_e,
    int* __restrict__ tile_m0, int* __restrict__ tile_r0)
{
    __shared__ int lc[NEXP];
    const int t = threadIdx.x;
    if (t < NEXP) lc[t] = 0;
    __syncthreads();

    int e0 = sel[t * 4 + 0], e1 = sel[t * 4 + 1];
    int e2 = sel[t * 4 + 2], e3 = sel[t * 4 + 3];
    int p0 = atomicAdd(&lc[e0], 1);
    int p1 = atomicAdd(&lc[e1], 1);
    int p2 = atomicAdd(&lc[e2], 1);
    int p3 = atomicAdd(&lc[e3], 1);
    tok_idx[e0 * NTOK + p0] = t;  slots[t * 4 + 0] = (e0 << 10) | p0;
    tok_idx[e1 * NTOK + p1] = t;  slots[t * 4 + 1] = (e1 << 10) | p1;
    tok_idx[e2 * NTOK + p2] = t;  slots[t * 4 + 2] = (e2 << 10) | p2;
    tok_idx[e3 * NTOK + p3] = t;  slots[t * 4 + 3] = (e3 << 10) | p3;

    __syncthreads();
    if (t < NEXP) counts[t] = lc[t];
    if (t == 0) {
        int nt = 0, row = 0;
        for (int e = 0; e <= NEXP; ++e) {
            const int c = (e == NEXP) ? NTOK : lc[e];
            for (int m0 = 0; m0 < c; m0 += 128) {
                tile_e[nt]  = e;
                tile_m0[nt] = m0;
                tile_r0[nt] = row + m0;
                ++nt;
            }
            row += c;
        }
        n_tiles[0] = nt;
    }
}

// Counted-vmcnt pipeline helpers (rule #18: sched_barrier after waitcnt/barrier)
#define WAITV8()  do { asm volatile("s_waitcnt vmcnt(8)" ::: "memory"); \
                       __builtin_amdgcn_sched_barrier(0); } while (0)
#define WAITV0()  do { asm volatile("s_waitcnt vmcnt(0)" ::: "memory"); \
                       __builtin_amdgcn_sched_barrier(0); } while (0)
#define RBAR()    do { __builtin_amdgcn_s_barrier(); \
                       __builtin_amdgcn_sched_barrier(0); } while (0)

// ---------------------------------------------------------------------------
// FFN1 (gload_lds, 128x128 tile, compact tile queue, counted-vmcnt pipeline).
// PURE GEMM.
// ---------------------------------------------------------------------------
__global__ __launch_bounds__(256, 2) void ffn1g(
    const _Float16* __restrict__ xh,
    const _Float16* __restrict__ w13h, const _Float16* __restrict__ w13sh,
    const int* __restrict__ counts, const int* __restrict__ tok_idx,
    const int* __restrict__ n_tiles, const int* __restrict__ tile_e,
    const int* __restrict__ tile_m0, const int* __restrict__ tile_r0,
    _Float16* __restrict__ h)
{
    const int tile = blockIdx.x >> 3;
    if (tile >= n_tiles[0]) return;
    const int y  = blockIdx.x & 7;
    const int e  = tile_e[tile];
    const int m0 = tile_m0[tile];
    const int rowbase = tile_r0[tile] - m0;   // so rowbase + m is the global row
    const int Me = (e == NEXP) ? NTOK : counts[e];
    const int g0 = y * 64;

    const int tid = threadIdx.x, lane = tid & 63;
    const int wid = tid >> 6;
    const int wm = wid >> 1, wn = wid & 1;
    const int li = lane & 15, rk = (lane >> 4) * 8;

    const _Float16* Wh = (e == NEXP) ? w13sh : (w13h + (size_t)e * (2 * INTERX) * DIMX);

    __shared__ _Float16 T[2][256 * 64];   // 64 KB

    const int lrow = lane >> 3;           // row within 8-row chunk
    const int lc   = (lane & 7) ^ lrow;   // pre-swizzled logical k-chunk
    const _Float16* src[8];
    int ldsoff[8];
#pragma unroll
    for (int j = 0; j < 8; ++j) {
        const int c = wid * 8 + j;        // chunk 0..31
        const int r = c * 8 + lrow;
        ldsoff[j] = c * 512;
        if (r < 128) {                    // A: gathered token row
            int ma = m0 + r; if (ma >= Me) ma = Me - 1;
            const int tok = (e == NEXP) ? ma : tok_idx[e * NTOK + ma];
            src[j] = xh + (size_t)tok * DIMX + lc * 8;
        } else {                          // B: w13 row in frag order
            const int rb = r - 128;
            const int bwn = rb >> 6, bf = (rb >> 4) & 3, bli = rb & 15;
            const int wrow = ((bf & 2) ? INTERX : 0) + g0 + bwn * 32 + (bf & 1) * 16 + bli;
            src[j] = Wh + (size_t)wrow * DIMX + lc * 8;
        }
    }

    f32x4 acc[4][4];
#pragma unroll
    for (int i = 0; i < 4; ++i)
#pragma unroll
        for (int f = 0; f < 4; ++f) acc[i][f] = (f32x4){0.f, 0.f, 0.f, 0.f};

    auto STAGE = [&](int b, int k0) {
#pragma unroll
        for (int j = 0; j < 8; ++j)
            gl_lds16(src[j] + k0, &T[b][ldsoff[j]]);
    };
    auto MM = [&](int b) {
#pragma unroll
        for (int kk = 0; kk < 64; kk += 32) {
            f16x8 afr[4], bfr[4];
#pragma unroll
            for (int i = 0; i < 4; ++i) {
                const int r = wm * 64 + i * 16 + li;
                afr[i] = *(const f16x8*)&T[b][SWZ(r, kk + rk)];
            }
#pragma unroll
            for (int f = 0; f < 4; ++f) {
                const int r = 128 + wn * 64 + f * 16 + li;
                bfr[f] = *(const f16x8*)&T[b][SWZ(r, kk + rk)];
            }
#pragma unroll
            for (int i = 0; i < 4; ++i)
#pragma unroll
                for (int f = 0; f < 4; ++f)
                    acc[i][f] = __builtin_amdgcn_mfma_f32_16x16x32_f16(
                        afr[i], bfr[f], acc[i][f], 0, 0, 0);
        }
    };

    STAGE(0, 0);
    WAITV0();
    RBAR();
    int cur = 0;
#pragma unroll
    for (int t = 0; t < DIMX / 64; ++t) {
        if (t + 1 < DIMX / 64) {
            STAGE(cur ^ 1, (t + 1) * 64);   // 8 loads stay in flight over MFMA
            WAITV8();                        // only waits the PREVIOUS stage
        } else {
            WAITV0();
        }
        RBAR();                              // all waves' prev-stage loads landed
        MM(cur);
        RBAR();                              // buf cur free for overwrite
        cur ^= 1;
    }

    // epilogue: frag f (gate) pairs with f+2 (up), same lane -> same h-col
#pragma unroll
    for (int i = 0; i < 4; ++i) {
#pragma unroll
        for (int q = 0; q < 4; ++q) {
            const int m = m0 + wm * 64 + i * 16 + (lane >> 4) * 4 + q;
            if (m >= Me) continue;
            _Float16* hp = h + (size_t)(rowbase + m) * INTERX + g0 + wn * 32 + li;
#pragma unroll
            for (int f = 0; f < 2; ++f) {
                const float g = acc[i][f][q];
                const float u = acc[i][f + 2][q];
                hp[f * 16] = (_Float16)(g * u / (1.f + __expf(-g)));
            }
        }
    }
}

// ---------------------------------------------------------------------------
// FFN2 (gload_lds, 128x128 tile, compact tile queue, counted-vmcnt pipeline):
// yc[row, n0..n0+127] = h_row @ w2_e^T (fp16 out).
// ---------------------------------------------------------------------------
__global__ __launch_bounds__(256, 2) void ffn2g(
    const _Float16* __restrict__ w2h, const _Float16* __restrict__ w2sh,
    const int* __restrict__ counts, const _Float16* __restrict__ h,
    const int* __restrict__ n_tiles, const int* __restrict__ tile_e,
    const int* __restrict__ tile_m0, const int* __restrict__ tile_r0,
    _Float16* __restrict__ yc)
{
    const int tile = blockIdx.x >> 3;
    if (tile >= n_tiles[0]) return;
    const int y  = blockIdx.x & 7;
    const int e  = tile_e[tile];
    const int m0 = tile_m0[tile];
    const int rowbase = tile_r0[tile] - m0;
    const int Me = (e == NEXP) ? NTOK : counts[e];
    const int n0 = y * 128;

    const int tid = threadIdx.x, lane = tid & 63;
    const int wid = tid >> 6;
    const int wm = wid >> 1, wn = wid & 1;
    const int li = lane & 15, rk = (lane >> 4) * 8;

    const _Float16* Wh = (e == NEXP) ? w2sh : (w2h + (size_t)e * DIMX * INTERX);

    __shared__ _Float16 T[2][256 * 64];   // 64 KB

    const int lrow = lane >> 3;
    const int lc   = (lane & 7) ^ lrow;
    const _Float16* src[8];
    int ldsoff[8];
#pragma unroll
    for (int j = 0; j < 8; ++j) {
        const int c = wid * 8 + j;
        const int r = c * 8 + lrow;
        ldsoff[j] = c * 512;
        if (r < 128) {                    // A: h row (rowbase+m0+r < 5120 always)
            src[j] = h + (size_t)(rowbase + m0 + r) * INTERX + lc * 8;
        } else {                          // B: w2 row n0 + rb (linear)
            const int rb = r - 128;
            src[j] = Wh + (size_t)(n0 + rb) * INTERX + lc * 8;
        }
    }

    f32x4 acc[4][4];
#pragma unroll
    for (int i = 0; i < 4; ++i)
#pragma unroll
        for (int f = 0; f < 4; ++f) acc[i][f] = (f32x4){0.f, 0.f, 0.f, 0.f};

    auto STAGE = [&](int b, int k0) {
#pragma unroll
        for (int j = 0; j < 8; ++j)
            gl_lds16(src[j] + k0, &T[b][ldsoff[j]]);
    };
    auto MM = [&](int b) {
#pragma unroll
        for (int kk = 0; kk < 64; kk += 32) {
            f16x8 afr[4], bfr[4];
#pragma unroll
            for (int i = 0; i < 4; ++i) {
                const int r = wm * 64 + i * 16 + li;
                afr[i] = *(const f16x8*)&T[b][SWZ(r, kk + rk)];
            }
#pragma unroll
            for (int f = 0; f < 4; ++f) {
                const int r = 128 + wn * 64 + f * 16 + li;
                bfr[f] = *(const f16x8*)&T[b][SWZ(r, kk + rk)];
            }
#pragma unroll
            for (int i = 0; i < 4; ++i)
#pragma unroll
                for (int f = 0; f < 4; ++f)
                    acc[i][f] = __builtin_amdgcn_mfma_f32_16x16x32_f16(
                        afr[i], bfr[f], acc[i][f], 0, 0, 0);
        }
    };

    STAGE(0, 0);
    WAITV0();
    RBAR();
    int cur = 0;
#pragma unroll
    for (int t = 0; t < INTERX / 64; ++t) {
        if (t + 1 < INTERX / 64) {
            STAGE(cur ^ 1, (t + 1) * 64);
            WAITV8();
        } else {
            WAITV0();
        }
        RBAR();
        MM(cur);
        RBAR();
        cur ^= 1;
    }

#pragma unroll
    for (int i = 0; i < 4; ++i) {
#pragma unroll
        for (int q = 0; q < 4; ++q) {
            const int m = m0 + wm * 64 + i * 16 + (lane >> 4) * 4 + q;
            if (m >= Me) continue;
            _Float16* yp = yc + (size_t)(rowbase + m) * DIMX + n0 + wn * 64 + li;
#pragma unroll
            for (int f = 0; f < 4; ++f)
                yp[f * 16] = (_Float16)acc[i][f][q];
        }
    }
}

// ---------------------------------------------------------------------------
// Combine: out[t,:] = yc[shared_row(t),:] + sum_k wq[t,k] * yc[row(t,k),:]
// ---------------------------------------------------------------------------
__global__ __launch_bounds__(256) void combine(
    const int* __restrict__ counts,
    const int* __restrict__ slots,
    const float* __restrict__ wq,
    const _Float16* __restrict__ yc,
    float* __restrict__ out)
{
    __shared__ int soff[NEXP];
    if (threadIdx.x < NEXP) {
        int o = 0;
        for (int i = 0; i < (int)threadIdx.x; ++i) o += counts[i];
        soff[threadIdx.x] = o;
    }
    __syncthreads();

    const int t = blockIdx.x;
    const int tid = threadIdx.x;                 // 256 threads x 4 cols = 1024
    const f16x4v* ycv = (const f16x4v*)yc;
    const f16x4v b = ycv[(size_t)(4096 + t) * 256 + tid];
    float a0 = (float)b[0], a1 = (float)b[1], a2 = (float)b[2], a3 = (float)b[3];
#pragma unroll
    for (int k = 0; k < 4; ++k) {
        const int s   = slots[t * 4 + k];
        const int e   = s >> 10, pos = s & 1023;
        const float w = wq[t * 4 + k];
        const f16x4v v = ycv[(size_t)(soff[e] + pos) * 256 + tid];
        a0 = fmaf(w, (float)v[0], a0); a1 = fmaf(w, (float)v[1], a1);
        a2 = fmaf(w, (float)v[2], a2); a3 = fmaf(w, (float)v[3], a3);
    }
    ((float4*)out)[(size_t)t * 256 + tid] = make_float4(a0, a1, a2, a3);
}

// ---------------------------------------------------------------------------
extern "C" void kernel_launch(void* const* d_in, const int* in_sizes, int n_in,
                              void* d_out, int out_size, void* d_ws, size_t ws_size,
                              hipStream_t stream)
{
    const float* x    = (const float*)d_in[0];
    // d_in[1] = input_ids (unused)
    const float* gw   = (const float*)d_in[2];
    const float* gb   = (const float*)d_in[3];
    const float* w13  = (const float*)d_in[4];
    const float* w2   = (const float*)d_in[5];
    const float* w13s = (const float*)d_in[6];
    const float* w2s  = (const float*)d_in[7];
    float* out = (float*)d_out;

    char* ws = (char*)d_ws;
    int*       counts  = (int*)(ws + WS_COUNTS);
    int*       tok_idx = (int*)(ws + WS_TOKIDX);
    int*       slots   = (int*)(ws + WS_SLOTS);
    float*     wq      = (float*)(ws + WS_WQ);
    int*       sel     = (int*)(ws + WS_SEL);
    int*       n_tiles = (int*)(ws + WS_NT);
    int*       tile_e  = (int*)(ws + WS_TE);
    int*       tile_m0 = (int*)(ws + WS_TM);
    int*       tile_r0 = (int*)(ws + WS_TR);
    _Float16*  h       = (_Float16*)(ws + WS_H);
    _Float16*  yc      = (_Float16*)(ws + WS_YC);
    _Float16*  dh      = (_Float16*)(ws + WS_F16);
    _Float16*  w13h    = dh;
    _Float16*  w2h     = w13h + N_W13;
    _Float16*  w13sh   = w2h + N_W2;
    _Float16*  w2sh    = w13sh + N_W13S;
    _Float16*  xh      = w2sh + N_W2S;

    // Fused gate + FULL weight conversion (3 populations, two 2-seg bodies)
    gate_cvt<<<GATE_BLOCKS + CVT13_BLOCKS + CVT2_BLOCKS, 256, 0, stream>>>(
        x, gw, gb, w13, w2, w13s, w2s, sel, wq, dh, xh);
    build<<<1, 1024, 0, stream>>>(sel, counts, tok_idx, slots,
                                  n_tiles, tile_e, tile_m0, tile_r0);

    // Pure GEMMs (compact tile queue, contiguous active ids)
    ffn1g<<<FFN_BLOCKS, 256, 0, stream>>>(xh, w13h, w13sh, counts, tok_idx,
                                          n_tiles, tile_e, tile_m0, tile_r0, h);
    ffn2g<<<FFN_BLOCKS, 256, 0, stream>>>(w2h, w2sh, counts, h,
                                          n_tiles, tile_e, tile_m0, tile_r0, yc);
    combine<<<NTOK, 256, 0, stream>>>(counts, slots, wq, yc, out);
}

// Round 28
// 80.650 us; speedup vs baseline: 1.0787x; 1.0312x over previous
//
#include <hip/hip_runtime.h>
#include <hip/hip_bf16.h>
#include <math.h>

// Problem constants
#define NTOK   1024      // 2*512 tokens
#define DIMX   1024
#define INTERX 512
#define NEXP   16
#define RSCALE 2.5f

typedef _Float16 f16x8 __attribute__((ext_vector_type(8)));
typedef _Float16 f16x4v __attribute__((ext_vector_type(4)));
typedef float    f32x4 __attribute__((ext_vector_type(4)));

// fp16 conversion region segment sizes (elements); layout [w13|w2|w13s|w2s|x]
#define N_W13  (NEXP * 2 * INTERX * DIMX)   // 16,777,216
#define N_W2   (NEXP * DIMX * INTERX)       //  8,388,608
#define N_W13S (2 * INTERX * DIMX)          //  1,048,576
#define N_W2S  (DIMX * INTERX)              //    524,288
#define N_X    (NTOK * DIMX)                //  1,048,576
#define N_CVT  ((size_t)N_W13 + N_W2 + N_W13S + N_W2S + N_X)

// ws layout (bytes) — proven
#define WS_COUNTS  0                                   // int[16]
#define WS_TOKIDX  256                                 // int[16*1024]
#define WS_SLOTS   (WS_TOKIDX + NEXP * NTOK * 4)       // int[1024*4]
#define WS_WQ      (WS_SLOTS + NTOK * 16)              // float[1024*4]
#define WS_SEL     (WS_WQ + NTOK * 16)                 // int[1024*4]
#define WS_NT      (WS_SEL + NTOK * 16)                // int[1]
#define WS_TE      (WS_NT + 64)                        // int[256]
#define WS_TM      (WS_TE + 1024)                      // int[256]
#define WS_TR      (WS_TM + 1024)                      // int[256]
#define WS_H       (WS_TR + 1024)                      // _Float16[5120*512]
#define WS_YC      (WS_H + (size_t)5120 * 512 * 2)     // _Float16[5120*1024] (4B/elem region)
#define WS_F16     (WS_YC + (size_t)5120 * 1024 * 4)   // _Float16[N_CVT]

// XOR-swizzled LDS addressing: row stride 64 halves (128B), k granule 8 halves.
#define SWZ(r, k) ((r) * 64 + ((k) ^ (((r) & 7) << 3)))

// grids: gate 256 blocks; w13|w13s cvt = 17,825,792 elems = 2176 blocks
#define GATE_BLOCKS  256
#define CVT13_BLOCKS 2176
#define FFN_BLOCKS   1088

__device__ __forceinline__ f16x8 ldcvt(const float* __restrict__ p) {
    const float4 a = *(const float4*)p;
    const float4 b = *(const float4*)(p + 4);
    return (f16x8){(_Float16)a.x, (_Float16)a.y, (_Float16)a.z, (_Float16)a.w,
                   (_Float16)b.x, (_Float16)b.y, (_Float16)b.z, (_Float16)b.w};
}

__device__ __forceinline__ f16x8 cvt8(const float4& a, const float4& b) {
    return (f16x8){(_Float16)a.x, (_Float16)a.y, (_Float16)a.z, (_Float16)a.w,
                   (_Float16)b.x, (_Float16)b.y, (_Float16)b.z, (_Float16)b.w};
}

// Direct global->LDS async copy, 16B per lane.
__device__ __forceinline__ void gl_lds16(const _Float16* g, _Float16* l) {
    __builtin_amdgcn_global_load_lds(
        (const __attribute__((address_space(1))) void*)g,
        (__attribute__((address_space(3))) void*)l, 16, 0, 0);
}

// 2-segment streaming cvt body with forced load-all-then-store-all.
__device__ __forceinline__ void cvt_body(
    size_t base8, size_t stride8,
    const float* __restrict__ sA, size_t nA, size_t dA,   // segment A
    const float* __restrict__ sB, size_t dB,              // segment B (tail)
    _Float16* __restrict__ dh)
{
    const float* s0; const float* s1; const float* s2; const float* s3;
    size_t d0, d1, d2, d3;
    {
        size_t off = (base8 + 0 * stride8) * 8;
        if (off < nA) { s0 = sA + off; d0 = dA + off; }
        else          { s0 = sB + (off - nA); d0 = dB + (off - nA); }
        off = (base8 + 1 * stride8) * 8;
        if (off < nA) { s1 = sA + off; d1 = dA + off; }
        else          { s1 = sB + (off - nA); d1 = dB + (off - nA); }
        off = (base8 + 2 * stride8) * 8;
        if (off < nA) { s2 = sA + off; d2 = dA + off; }
        else          { s2 = sB + (off - nA); d2 = dB + (off - nA); }
        off = (base8 + 3 * stride8) * 8;
        if (off < nA) { s3 = sA + off; d3 = dA + off; }
        else          { s3 = sB + (off - nA); d3 = dB + (off - nA); }
    }
    const float4 a0 = *(const float4*)s0, b0 = *(const float4*)(s0 + 4);
    const float4 a1 = *(const float4*)s1, b1 = *(const float4*)(s1 + 4);
    const float4 a2 = *(const float4*)s2, b2 = *(const float4*)(s2 + 4);
    const float4 a3 = *(const float4*)s3, b3 = *(const float4*)(s3 + 4);
    __builtin_amdgcn_sched_barrier(0);    // all 8 loads in flight before stores
    *(f16x8*)(dh + d0) = cvt8(a0, b0);
    *(f16x8*)(dh + d1) = cvt8(a1, b1);
    *(f16x8*)(dh + d2) = cvt8(a2, b2);
    *(f16x8*)(dh + d3) = cvt8(a3, b3);
}

// ---------------------------------------------------------------------------
// Fused: blocks [0,256) = gating (+ x->fp16); blocks [256, 256+2176) =
// streaming fp32->fp16 of [w13 | w13s]. (w2|w2s converted by ffn1g's
// dead blocks.)
// ---------------------------------------------------------------------------
__global__ __launch_bounds__(256) void gate_cvt13(
    const float* __restrict__ x, const float* __restrict__ gw,
    const float* __restrict__ gb,
    const float* __restrict__ w13, const float* __restrict__ w13s,
    int* __restrict__ sel, float* __restrict__ wq,
    _Float16* __restrict__ dh, _Float16* __restrict__ xh)
{
    if (blockIdx.x >= GATE_BLOCKS) {
        const size_t base8 = (size_t)(blockIdx.x - GATE_BLOCKS) * 256 + threadIdx.x;
        cvt_body(base8, (size_t)CVT13_BLOCKS * 256,
                 w13, N_W13, 0,                              // w13 -> dh[0..)
                 w13s, (size_t)N_W13 + N_W2,                 // w13s -> dh[N_W13+N_W2..)
                 dh);
        return;
    }

    // ---- gating: one wave per token (4 per block), atomic-free ----
    const int t    = blockIdx.x * 4 + (threadIdx.x >> 6);
    const int lane = threadIdx.x & 63;
    const int e    = lane & 15;
    const int q    = lane >> 4;

    const float4* xq = (const float4*)(x + (size_t)t * DIMX) + q * 64;
    const float4* gq = (const float4*)(gw + (size_t)e * DIMX) + q * 64;
    float s0 = 0.f, s1 = 0.f, s2 = 0.f, s3 = 0.f;
#pragma unroll 8
    for (int i = 0; i < 64; i += 2) {
        const float4 a = xq[i],     b = gq[i];
        const float4 c = xq[i + 1], d = gq[i + 1];
        s0 = fmaf(a.x, b.x, s0); s1 = fmaf(a.y, b.y, s1);
        s2 = fmaf(a.z, b.z, s2); s3 = fmaf(a.w, b.w, s3);
        s0 = fmaf(c.x, d.x, s0); s1 = fmaf(c.y, d.y, s1);
        s2 = fmaf(c.z, d.z, s2); s3 = fmaf(c.w, d.w, s3);
    }
    float acc = (s0 + s1) + (s2 + s3);
    acc += __shfl_xor(acc, 16);
    acc += __shfl_xor(acc, 32);

    {   // fp16 copy of x: lane owns 16 elements of its token's row
        const float* xr = x + (size_t)t * DIMX + lane * 16;
        *(f16x8*)(xh + (size_t)t * DIMX + lane * 16)     = ldcvt(xr);
        *(f16x8*)(xh + (size_t)t * DIMX + lane * 16 + 8) = ldcvt(xr + 8);
    }

    const float sv = 1.f / (1.f + __expf(-acc));
    float v = (lane < 16) ? (sv + gb[e]) : -1e30f;

    float wk0, wk1, wk2, wk3; int ek0, ek1, ek2, ek3;
    float wsum = 0.f;
#pragma unroll
    for (int k = 0; k < 4; ++k) {
        float bestv = v; int besti = lane;
#pragma unroll
        for (int off = 8; off >= 1; off >>= 1) {
            const float ov = __shfl_xor(bestv, off);
            const int   oi = __shfl_xor(besti, off);
            if (ov > bestv || (ov == bestv && oi < besti)) { bestv = ov; besti = oi; }
        }
        besti = __shfl(besti, 0);
        const float sbest = __shfl(sv, besti);
        if (k == 0) { wk0 = sbest; ek0 = besti; }
        if (k == 1) { wk1 = sbest; ek1 = besti; }
        if (k == 2) { wk2 = sbest; ek2 = besti; }
        if (k == 3) { wk3 = sbest; ek3 = besti; }
        wsum += sbest;
        if (lane == besti) v = -1e30f;
    }
    const float scale = RSCALE / wsum;

    if (lane == 0) {
        sel[t * 4 + 0] = ek0;  wq[t * 4 + 0] = wk0 * scale;
        sel[t * 4 + 1] = ek1;  wq[t * 4 + 1] = wk1 * scale;
        sel[t * 4 + 2] = ek2;  wq[t * 4 + 2] = wk2 * scale;
        sel[t * 4 + 3] = ek3;  wq[t * 4 + 3] = wk3 * scale;
    }
}

// ---------------------------------------------------------------------------
// Build per-expert token lists + COMPACT M-TILE QUEUE (e, m0, row0).
// ONE block, LDS atomics only.
// ---------------------------------------------------------------------------
__global__ __launch_bounds__(1024) void build(
    const int* __restrict__ sel,
    int* __restrict__ counts, int* __restrict__ tok_idx,
    int* __restrict__ slots,
    int* __restrict__ n_tiles, int* __restrict__ tile_e,
    int* __restrict__ tile_m0, int* __restrict__ tile_r0)
{
    __shared__ int lc[NEXP];
    const int t = threadIdx.x;
    if (t < NEXP) lc[t] = 0;
    __syncthreads();

    int e0 = sel[t * 4 + 0], e1 = sel[t * 4 + 1];
    int e2 = sel[t * 4 + 2], e3 = sel[t * 4 + 3];
    int p0 = atomicAdd(&lc[e0], 1);
    int p1 = atomicAdd(&lc[e1], 1);
    int p2 = atomicAdd(&lc[e2], 1);
    int p3 = atomicAdd(&lc[e3], 1);
    tok_idx[e0 * NTOK + p0] = t;  slots[t * 4 + 0] = (e0 << 10) | p0;
    tok_idx[e1 * NTOK + p1] = t;  slots[t * 4 + 1] = (e1 << 10) | p1;
    tok_idx[e2 * NTOK + p2] = t;  slots[t * 4 + 2] = (e2 << 10) | p2;
    tok_idx[e3 * NTOK + p3] = t;  slots[t * 4 + 3] = (e3 << 10) | p3;

    __syncthreads();
    if (t < NEXP) counts[t] = lc[t];
    if (t == 0) {
        int nt = 0, row = 0;
        for (int e = 0; e <= NEXP; ++e) {
            const int c = (e == NEXP) ? NTOK : lc[e];
            for (int m0 = 0; m0 < c; m0 += 128) {
                tile_e[nt]  = e;
                tile_m0[nt] = m0;
                tile_r0[nt] = row + m0;
                ++nt;
            }
            row += c;
        }
        n_tiles[0] = nt;
    }
}

// Counted-vmcnt pipeline helpers (rule #18: sched_barrier after waitcnt/barrier)
#define WAITV8()  do { asm volatile("s_waitcnt vmcnt(8)" ::: "memory"); \
                       __builtin_amdgcn_sched_barrier(0); } while (0)
#define WAITV0()  do { asm volatile("s_waitcnt vmcnt(0)" ::: "memory"); \
                       __builtin_amdgcn_sched_barrier(0); } while (0)
#define RBAR()    do { __builtin_amdgcn_s_barrier(); \
                       __builtin_amdgcn_sched_barrier(0); } while (0)

// ---------------------------------------------------------------------------
// FFN1 (gload_lds, 128x128 tile, compact tile queue, counted-vmcnt pipeline)
// + DEAD-BLOCK CVT: blocks with tile >= n_tiles grid-stride the w2|w2s
// fp32->fp16 conversion.
// ---------------------------------------------------------------------------
__global__ __launch_bounds__(256, 2) void ffn1g(
    const _Float16* __restrict__ xh,
    const _Float16* __restrict__ w13h, const _Float16* __restrict__ w13sh,
    const float* __restrict__ w2f, const float* __restrict__ w2sf,
    const int* __restrict__ counts, const int* __restrict__ tok_idx,
    const int* __restrict__ n_tiles, const int* __restrict__ tile_e,
    const int* __restrict__ tile_m0, const int* __restrict__ tile_r0,
    _Float16* __restrict__ dh, _Float16* __restrict__ h)
{
    const int nt   = n_tiles[0];
    const int tile = blockIdx.x >> 3;
    if (tile >= nt) {
        // ---- dead block: convert w2|w2s (grid-stride over the dead set) ----
        const int    nd      = FFN_BLOCKS - 8 * nt;          // # dead blocks
        const size_t d       = blockIdx.x - 8 * nt;          // dead index
        const size_t stride8 = (size_t)nd * 256;
        const size_t total8  = (size_t)(N_W2 + N_W2S) / 8;   // 1,114,112
        for (size_t i8 = d * 256 + threadIdx.x; i8 < total8; i8 += stride8) {
            const size_t off = i8 * 8;
            if (off < N_W2) {
                *(f16x8*)(dh + (size_t)N_W13 + off) = ldcvt(w2f + off);
            } else {
                const size_t o2 = off - N_W2;
                *(f16x8*)(dh + (size_t)N_W13 + N_W2 + N_W13S + o2) = ldcvt(w2sf + o2);
            }
        }
        return;
    }
    const int y  = blockIdx.x & 7;
    const int e  = tile_e[tile];
    const int m0 = tile_m0[tile];
    const int rowbase = tile_r0[tile] - m0;   // so rowbase + m is the global row
    const int Me = (e == NEXP) ? NTOK : counts[e];
    const int g0 = y * 64;

    const int tid = threadIdx.x, lane = tid & 63;
    const int wid = tid >> 6;
    const int wm = wid >> 1, wn = wid & 1;
    const int li = lane & 15, rk = (lane >> 4) * 8;

    const _Float16* Wh = (e == NEXP) ? w13sh : (w13h + (size_t)e * (2 * INTERX) * DIMX);

    __shared__ _Float16 T[2][256 * 64];   // 64 KB

    const int lrow = lane >> 3;           // row within 8-row chunk
    const int lc   = (lane & 7) ^ lrow;   // pre-swizzled logical k-chunk
    const _Float16* src[8];
    int ldsoff[8];
#pragma unroll
    for (int j = 0; j < 8; ++j) {
        const int c = wid * 8 + j;        // chunk 0..31
        const int r = c * 8 + lrow;
        ldsoff[j] = c * 512;
        if (r < 128) {                    // A: gathered token row
            int ma = m0 + r; if (ma >= Me) ma = Me - 1;
            const int tok = (e == NEXP) ? ma : tok_idx[e * NTOK + ma];
            src[j] = xh + (size_t)tok * DIMX + lc * 8;
        } else {                          // B: w13 row in frag order
            const int rb = r - 128;
            const int bwn = rb >> 6, bf = (rb >> 4) & 3, bli = rb & 15;
            const int wrow = ((bf & 2) ? INTERX : 0) + g0 + bwn * 32 + (bf & 1) * 16 + bli;
            src[j] = Wh + (size_t)wrow * DIMX + lc * 8;
        }
    }

    f32x4 acc[4][4];
#pragma unroll
    for (int i = 0; i < 4; ++i)
#pragma unroll
        for (int f = 0; f < 4; ++f) acc[i][f] = (f32x4){0.f, 0.f, 0.f, 0.f};

    auto STAGE = [&](int b, int k0) {
#pragma unroll
        for (int j = 0; j < 8; ++j)
            gl_lds16(src[j] + k0, &T[b][ldsoff[j]]);
    };
    auto MM = [&](int b) {
#pragma unroll
        for (int kk = 0; kk < 64; kk += 32) {
            f16x8 afr[4], bfr[4];
#pragma unroll
            for (int i = 0; i < 4; ++i) {
                const int r = wm * 64 + i * 16 + li;
                afr[i] = *(const f16x8*)&T[b][SWZ(r, kk + rk)];
            }
#pragma unroll
            for (int f = 0; f < 4; ++f) {
                const int r = 128 + wn * 64 + f * 16 + li;
                bfr[f] = *(const f16x8*)&T[b][SWZ(r, kk + rk)];
            }
#pragma unroll
            for (int i = 0; i < 4; ++i)
#pragma unroll
                for (int f = 0; f < 4; ++f)
                    acc[i][f] = __builtin_amdgcn_mfma_f32_16x16x32_f16(
                        afr[i], bfr[f], acc[i][f], 0, 0, 0);
        }
    };

    STAGE(0, 0);
    WAITV0();
    RBAR();
    int cur = 0;
#pragma unroll
    for (int t = 0; t < DIMX / 64; ++t) {
        if (t + 1 < DIMX / 64) {
            STAGE(cur ^ 1, (t + 1) * 64);   // 8 loads stay in flight over MFMA
            WAITV8();                        // only waits the PREVIOUS stage
        } else {
            WAITV0();
        }
        RBAR();                              // all waves' prev-stage loads landed
        MM(cur);
        RBAR();                              // buf cur free for overwrite
        cur ^= 1;
    }

    // epilogue: frag f (gate) pairs with f+2 (up), same lane -> same h-col
#pragma unroll
    for (int i = 0; i < 4; ++i) {
#pragma unroll
        for (int q = 0; q < 4; ++q) {
            const int m = m0 + wm * 64 + i * 16 + (lane >> 4) * 4 + q;
            if (m >= Me) continue;
            _Float16* hp = h + (size_t)(rowbase + m) * INTERX + g0 + wn * 32 + li;
#pragma unroll
            for (int f = 0; f < 2; ++f) {
                const float g = acc[i][f][q];
                const float u = acc[i][f + 2][q];
                hp[f * 16] = (_Float16)(g * u / (1.f + __expf(-g)));
            }
        }
    }
}

// ---------------------------------------------------------------------------
// FFN2 (gload_lds, 128x128 tile, compact tile queue, counted-vmcnt pipeline):
// yc[row, n0..n0+127] = h_row @ w2_e^T (fp16 out).
// ---------------------------------------------------------------------------
__global__ __launch_bounds__(256, 2) void ffn2g(
    const _Float16* __restrict__ w2h, const _Float16* __restrict__ w2sh,
    const int* __restrict__ counts, const _Float16* __restrict__ h,
    const int* __restrict__ n_tiles, const int* __restrict__ tile_e,
    const int* __restrict__ tile_m0, const int* __restrict__ tile_r0,
    _Float16* __restrict__ yc)
{
    const int tile = blockIdx.x >> 3;
    if (tile >= n_tiles[0]) return;
    const int y  = blockIdx.x & 7;
    const int e  = tile_e[tile];
    const int m0 = tile_m0[tile];
    const int rowbase = tile_r0[tile] - m0;
    const int Me = (e == NEXP) ? NTOK : counts[e];
    const int n0 = y * 128;

    const int tid = threadIdx.x, lane = tid & 63;
    const int wid = tid >> 6;
    const int wm = wid >> 1, wn = wid & 1;
    const int li = lane & 15, rk = (lane >> 4) * 8;

    const _Float16* Wh = (e == NEXP) ? w2sh : (w2h + (size_t)e * DIMX * INTERX);

    __shared__ _Float16 T[2][256 * 64];   // 64 KB

    const int lrow = lane >> 3;
    const int lc   = (lane & 7) ^ lrow;
    const _Float16* src[8];
    int ldsoff[8];
#pragma unroll
    for (int j = 0; j < 8; ++j) {
        const int c = wid * 8 + j;
        const int r = c * 8 + lrow;
        ldsoff[j] = c * 512;
        if (r < 128) {                    // A: h row (rowbase+m0+r < 5120 always)
            src[j] = h + (size_t)(rowbase + m0 + r) * INTERX + lc * 8;
        } else {                          // B: w2 row n0 + rb (linear)
            const int rb = r - 128;
            src[j] = Wh + (size_t)(n0 + rb) * INTERX + lc * 8;
        }
    }

    f32x4 acc[4][4];
#pragma unroll
    for (int i = 0; i < 4; ++i)
#pragma unroll
        for (int f = 0; f < 4; ++f) acc[i][f] = (f32x4){0.f, 0.f, 0.f, 0.f};

    auto STAGE = [&](int b, int k0) {
#pragma unroll
        for (int j = 0; j < 8; ++j)
            gl_lds16(src[j] + k0, &T[b][ldsoff[j]]);
    };
    auto MM = [&](int b) {
#pragma unroll
        for (int kk = 0; kk < 64; kk += 32) {
            f16x8 afr[4], bfr[4];
#pragma unroll
            for (int i = 0; i < 4; ++i) {
                const int r = wm * 64 + i * 16 + li;
                afr[i] = *(const f16x8*)&T[b][SWZ(r, kk + rk)];
            }
#pragma unroll
            for (int f = 0; f < 4; ++f) {
                const int r = 128 + wn * 64 + f * 16 + li;
                bfr[f] = *(const f16x8*)&T[b][SWZ(r, kk + rk)];
            }
#pragma unroll
            for (int i = 0; i < 4; ++i)
#pragma unroll
                for (int f = 0; f < 4; ++f)
                    acc[i][f] = __builtin_amdgcn_mfma_f32_16x16x32_f16(
                        afr[i], bfr[f], acc[i][f], 0, 0, 0);
        }
    };

    STAGE(0, 0);
    WAITV0();
    RBAR();
    int cur = 0;
#pragma unroll
    for (int t = 0; t < INTERX / 64; ++t) {
        if (t + 1 < INTERX / 64) {
            STAGE(cur ^ 1, (t + 1) * 64);
            WAITV8();
        } else {
            WAITV0();
        }
        RBAR();
        MM(cur);
        RBAR();
        cur ^= 1;
    }

#pragma unroll
    for (int i = 0; i < 4; ++i) {
#pragma unroll
        for (int q = 0; q < 4; ++q) {
            const int m = m0 + wm * 64 + i * 16 + (lane >> 4) * 4 + q;
            if (m >= Me) continue;
            _Float16* yp = yc + (size_t)(rowbase + m) * DIMX + n0 + wn * 64 + li;
#pragma unroll
            for (int f = 0; f < 4; ++f)
                yp[f * 16] = (_Float16)acc[i][f][q];
        }
    }
}

// ---------------------------------------------------------------------------
// Combine: out[t,:] = yc[shared_row(t),:] + sum_k wq[t,k] * yc[row(t,k),:]
// ---------------------------------------------------------------------------
__global__ __launch_bounds__(256) void combine(
    const int* __restrict__ counts,
    const int* __restrict__ slots,
    const float* __restrict__ wq,
    const _Float16* __restrict__ yc,
    float* __restrict__ out)
{
    __shared__ int soff[NEXP];
    if (threadIdx.x < NEXP) {
        int o = 0;
        for (int i = 0; i < (int)threadIdx.x; ++i) o += counts[i];
        soff[threadIdx.x] = o;
    }
    __syncthreads();

    const int t = blockIdx.x;
    const int tid = threadIdx.x;                 // 256 threads x 4 cols = 1024
    const f16x4v* ycv = (const f16x4v*)yc;
    const f16x4v b = ycv[(size_t)(4096 + t) * 256 + tid];
    float a0 = (float)b[0], a1 = (float)b[1], a2 = (float)b[2], a3 = (float)b[3];
#pragma unroll
    for (int k = 0; k < 4; ++k) {
        const int s   = slots[t * 4 + k];
        const int e   = s >> 10, pos = s & 1023;
        const float w = wq[t * 4 + k];
        const f16x4v v = ycv[(size_t)(soff[e] + pos) * 256 + tid];
        a0 = fmaf(w, (float)v[0], a0); a1 = fmaf(w, (float)v[1], a1);
        a2 = fmaf(w, (float)v[2], a2); a3 = fmaf(w, (float)v[3], a3);
    }
    ((float4*)out)[(size_t)t * 256 + tid] = make_float4(a0, a1, a2, a3);
}

// ---------------------------------------------------------------------------
extern "C" void kernel_launch(void* const* d_in, const int* in_sizes, int n_in,
                              void* d_out, int out_size, void* d_ws, size_t ws_size,
                              hipStream_t stream)
{
    const float* x    = (const float*)d_in[0];
    // d_in[1] = input_ids (unused)
    const float* gw   = (const float*)d_in[2];
    const float* gb   = (const float*)d_in[3];
    const float* w13  = (const float*)d_in[4];
    const float* w2   = (const float*)d_in[5];
    const float* w13s = (const float*)d_in[6];
    const float* w2s  = (const float*)d_in[7];
    float* out = (float*)d_out;

    char* ws = (char*)d_ws;
    int*       counts  = (int*)(ws + WS_COUNTS);
    int*       tok_idx = (int*)(ws + WS_TOKIDX);
    int*       slots   = (int*)(ws + WS_SLOTS);
    float*     wq      = (float*)(ws + WS_WQ);
    int*       sel     = (int*)(ws + WS_SEL);
    int*       n_tiles = (int*)(ws + WS_NT);
    int*       tile_e  = (int*)(ws + WS_TE);
    int*       tile_m0 = (int*)(ws + WS_TM);
    int*       tile_r0 = (int*)(ws + WS_TR);
    _Float16*  h       = (_Float16*)(ws + WS_H);
    _Float16*  yc      = (_Float16*)(ws + WS_YC);
    _Float16*  dh      = (_Float16*)(ws + WS_F16);
    _Float16*  w13h    = dh;
    _Float16*  w2h     = w13h + N_W13;
    _Float16*  w13sh   = w2h + N_W2;
    _Float16*  w2sh    = w13sh + N_W13S;
    _Float16*  xh      = w2sh + N_W2S;

    // Fused gate + w13 conversion (gate hides under the BW-bound cvt)
    gate_cvt13<<<GATE_BLOCKS + CVT13_BLOCKS, 256, 0, stream>>>(
        x, gw, gb, w13, w13s, sel, wq, dh, xh);
    build<<<1, 1024, 0, stream>>>(sel, counts, tok_idx, slots,
                                  n_tiles, tile_e, tile_m0, tile_r0);

    // FFN1: active tiles do MFMA; dead blocks (tile >= n_tiles) convert w2|w2s
    // co-resident with the MFMA blocks.
    ffn1g<<<FFN_BLOCKS, 256, 0, stream>>>(
        xh, w13h, w13sh, w2, w2s, counts, tok_idx,
        n_tiles, tile_e, tile_m0, tile_r0, dh, h);
    ffn2g<<<FFN_BLOCKS, 256, 0, stream>>>(w2h, w2sh, counts, h,
                                          n_tiles, tile_e, tile_m0, tile_r0, yc);
    combine<<<NTOK, 256, 0, stream>>>(counts, slots, wq, yc, out);
}